// Round 4
// baseline (245.787 us; speedup 1.0000x reference)
//
#include <hip/hip_runtime.h>

// MHA forward. L=S=1024, N=4, E=1024, H=16, hd=64, B=N*H=64, M=L*N=4096
// Inputs fp32, outputs fp32 (out0=attn_output 4.19M, out1=attn_weights 4.19M @+4194304).
// Round 10: three different qkv K-loop schedules (r6 54.6 / r8 61.5 / r9 59.1)
// all ~invariant at MfmaUtil ~16% -> K-loop exonerated; shared cost = scatter
// epilogue (v-blocks: 64 lanes x 2B stores to 64 distinct lines -> ~64 txns per
// wave-store, ~16k serialized txn-cycles per v-block). This round: epilogue
// coalescing via LDS re-stage. After the K-loop the 32KB staging LDS is reused
// as an output tile: f2bf(acc+bias) scattered into LDS (cheap, XOR-swizzled),
// then contiguous short8 (16B) global stores (qh/kh: 1KB/wave-instr; vt: 16x64B
// segments/wave-instr). Same values, same addresses -> bit-identical numerics.
// K-loop, attention, convert, out_gemm unchanged.
typedef unsigned short u16;
typedef __attribute__((ext_vector_type(8))) short short8;   // 8 bf16 (4 VGPRs)
typedef __attribute__((ext_vector_type(4))) float f32x4;    // MFMA accumulator

__device__ __forceinline__ u16 f2bf(float f) {  // RNE
  unsigned int i = __float_as_uint(f);
  i += 0x7fffu + ((i >> 16) & 1u);
  return (u16)(i >> 16);
}

__device__ __forceinline__ short8 cvt8(const float* p) {
  float4 a = ((const float4*)p)[0];
  float4 b = ((const float4*)p)[1];
  short8 r;
  r[0] = (short)f2bf(a.x); r[1] = (short)f2bf(a.y);
  r[2] = (short)f2bf(a.z); r[3] = (short)f2bf(a.w);
  r[4] = (short)f2bf(b.x); r[5] = (short)f2bf(b.y);
  r[6] = (short)f2bf(b.z); r[7] = (short)f2bf(b.w);
  return r;
}

// ---------------------------------------------------------------------------
// Kernel 0: one-shot fp32 -> bf16 conversion of q/k/v/W_in/W_out. (unchanged)
// ---------------------------------------------------------------------------
__global__ __launch_bounds__(256) void convert_bf16(
    const float* __restrict__ q, const float* __restrict__ k,
    const float* __restrict__ v, const float* __restrict__ Wi,
    const float* __restrict__ Wo,
    u16* __restrict__ qb, u16* __restrict__ kb, u16* __restrict__ vb,
    u16* __restrict__ Wib, u16* __restrict__ Wob)
{
  const float* src; u16* dst; int len8;
  switch (blockIdx.y) {
    case 0:  src = q;  dst = qb;  len8 = 524288; break;  // 4M elts
    case 1:  src = k;  dst = kb;  len8 = 524288; break;
    case 2:  src = v;  dst = vb;  len8 = 524288; break;
    case 3:  src = Wi; dst = Wib; len8 = 393216; break;  // 3M elts
    default: src = Wo; dst = Wob; len8 = 131072; break;  // 1M elts
  }
  int stride = gridDim.x * 256;
  for (int i = blockIdx.x * 256 + threadIdx.x; i < len8; i += stride)
    *(short8*)(dst + (size_t)i * 8) = cvt8(src + (size_t)i * 8);
}

// ---------------------------------------------------------------------------
// Kernel 1: packed QKV projection. K-loop: 128x128 tile, BK=32, 2-phase
// double-buffer (unchanged from round 9). NEW: coalesced epilogue via LDS
// re-stage (SH overlays the two staging buffers, 32 KB).
// C[m][j] = X[m][:].W[j][:] + bias[j]; M=4096, K=1024, J=3072 (bf16 inputs).
// ---------------------------------------------------------------------------
__global__ __launch_bounds__(256) void qkv_gemm(
    const u16* __restrict__ qb, const u16* __restrict__ kb,
    const u16* __restrict__ vb, const u16* __restrict__ W,
    const float* __restrict__ bias,
    u16* __restrict__ qh, u16* __restrict__ kh, u16* __restrict__ vt)
{
  __shared__ __align__(16) u16 SH[16384];   // 32 KB: K-loop staging + epilogue

  const int tid  = threadIdx.x;
  const int wave = tid >> 6;
  const int lane = tid & 63;
  const int r    = lane & 15;
  const int q4   = lane >> 4;
  const int wm   = wave >> 1;          // 0..1  (row quadrant)
  const int wn   = wave & 1;           // 0..1  (col quadrant)

  // XCD-chunked swizzle: one XCD covers 4 m-tiles x all j-tiles.
  const int orig = blockIdx.y * 24 + blockIdx.x;
  const int nid  = (orig & 7) * 96 + (orig >> 3);
  const int mt   = nid / 24;           // 0..31
  const int jt   = nid - mt * 24;      // 0..23
  const int src  = jt >> 3;            // 0=q, 1=k, 2=v
  const u16* X = (src == 0) ? qb : (src == 1) ? kb : vb;
  const int m0 = mt * 128;
  const int j0 = jt * 128;

  // staging: per gload_lds instr a wave covers 16 rows x 64B (1KB).
  const int lrow = lane >> 2;
  const int lchk = ((lane & 3) ^ ((lane >> 3) & 3)) << 4;   // byte offset
  const char* Xc = (const char*)X;
  const char* Wc = (const char*)W;

  // fragment-read: logical chunk q4 of row (..+r) lives at phys q4^((r>>1)&3)
  const int fchk = (q4 ^ ((r >> 1) & 3)) << 3;              // u16 offset

  f32x4 acc[4][4];
  #pragma unroll
  for (int a = 0; a < 4; ++a)
    #pragma unroll
    for (int b = 0; b < 4; ++b)
      acc[a][b] = (f32x4){0.f, 0.f, 0.f, 0.f};

  auto STAGE = [&](int buf, int kt) {
    const int kbyte = kt * 64;
    u16* Ad = SH + buf * 4096;
    u16* Bd = SH + 8192 + buf * 4096;
    #pragma unroll
    for (int i = 0; i < 2; ++i) {
      const int g = wave * 2 + i;      // 16-row group 0..7
      __builtin_amdgcn_global_load_lds(
          (const u16*)(Xc + (size_t)(m0 + g * 16 + lrow) * 2048 + kbyte + lchk),
          Ad + g * 512, 16, 0, 0);
      __builtin_amdgcn_global_load_lds(
          (const u16*)(Wc + (size_t)(j0 + g * 16 + lrow) * 2048 + kbyte + lchk),
          Bd + g * 512, 16, 0, 0);
    }
  };

  STAGE(0, 0);
  for (int kt = 0; kt < 32; ++kt) {
    const int cur = kt & 1;
    __syncthreads();                   // vmcnt(0) drain: buf[cur] staged;
                                       // all waves done reading buf[cur^1]
    if (kt < 31) STAGE(cur ^ 1, kt + 1);

    const u16* As = SH + cur * 4096;
    const u16* Bs = SH + 8192 + cur * 4096;
    short8 af[4], bf[4];
    #pragma unroll
    for (int mi = 0; mi < 4; ++mi)
      af[mi] = *(const short8*)(&As[(wm * 64 + mi * 16 + r) * 32 + fchk]);
    #pragma unroll
    for (int ji = 0; ji < 4; ++ji)
      bf[ji] = *(const short8*)(&Bs[(wn * 64 + ji * 16 + r) * 32 + fchk]);
    #pragma unroll
    for (int mi = 0; mi < 4; ++mi)
      #pragma unroll
      for (int ji = 0; ji < 4; ++ji)
        acc[mi][ji] = __builtin_amdgcn_mfma_f32_16x16x32_bf16(af[mi], bf[ji], acc[mi][ji], 0, 0, 0);
  }

  // ---- coalesced epilogue: acc -> LDS (permuted+swizzled) -> short8 stores.
  // Element mapping (same values/addresses as the old scatter epilogue):
  //   local m = wm*64+mi*16+q4*4+rr -> tt = wm*16+mi*4+q4 (t = mt*32+tt), n = rr
  //   local j = wn*64+ji*16+r       -> hq = j>>6 (h = h0+hq), d = j&63
  __syncthreads();                     // all waves done with K-loop LDS
  const int h0 = (j0 & 1023) >> 6;
  const int t0 = mt * 32;
  if (src < 2) {
    // LDS layout [n][hq][tt][d], d-chunks XOR-swizzled by tt&7
    #pragma unroll
    for (int mi = 0; mi < 4; ++mi) {
      const int tt = wm * 16 + mi * 4 + q4;
      #pragma unroll
      for (int ji = 0; ji < 4; ++ji) {
        const int jj = wn * 64 + ji * 16 + r;
        const int dd = jj & 63, hq = jj >> 6;
        const int cs = (((dd >> 3) ^ (tt & 7)) << 3) + (dd & 7);
        #pragma unroll
        for (int rr = 0; rr < 4; ++rr) {
          float v = acc[mi][ji][rr] + bias[j0 + jj];
          SH[((rr * 2 + hq) * 32 + tt) * 64 + cs] =
              (src == 0) ? f2bf(v * 0.125f) : f2bf(v);
        }
      }
    }
    __syncthreads();
    u16* dst = (src == 0) ? qh : kh;
    #pragma unroll
    for (int c = 0; c < 8; ++c) {
      const int cid = c * 256 + tid;   // consecutive lanes -> consecutive chunks
      const int nn = cid >> 9, hq = (cid >> 8) & 1, tt = (cid >> 3) & 31, dc = cid & 7;
      short8 vv = *(const short8*)(SH + ((nn * 2 + hq) * 32 + tt) * 64 +
                                   ((dc ^ (tt & 7)) << 3));
      *(short8*)(dst + (size_t)(nn * 16 + h0 + hq) * 65536 +
                 (size_t)(t0 + tt) * 64 + dc * 8) = vv;
    }
  } else {
    // LDS layout [bbv=n*2+hq][d][t] (t fast, 32 elts), t-chunks XOR'd by d&3
    #pragma unroll
    for (int mi = 0; mi < 4; ++mi) {
      const int tt = wm * 16 + mi * 4 + q4;
      const int tc = tt >> 3, toff = tt & 7;
      #pragma unroll
      for (int ji = 0; ji < 4; ++ji) {
        const int jj = wn * 64 + ji * 16 + r;
        const int dd = jj & 63, hq = jj >> 6;
        #pragma unroll
        for (int rr = 0; rr < 4; ++rr) {
          float v = acc[mi][ji][rr] + bias[j0 + jj];
          SH[((rr * 2 + hq) * 64 + dd) * 32 + ((tc ^ (dd & 3)) << 3) + toff] = f2bf(v);
        }
      }
    }
    __syncthreads();
    #pragma unroll
    for (int c = 0; c < 8; ++c) {
      const int cid = c * 256 + tid;
      const int bbv = cid >> 8, dd = (cid >> 2) & 63, tc = cid & 3;
      short8 vv = *(const short8*)(SH + (bbv * 64 + dd) * 32 +
                                   ((tc ^ (dd & 3)) << 3));
      const int bb = (bbv >> 1) * 16 + h0 + (bbv & 1);
      *(short8*)(vt + (size_t)bb * 65536 + (size_t)dd * 1024 + t0 + tc * 8) = vv;
    }
  }
}

// ---------------------------------------------------------------------------
// Kernel 2: attention context, MFMA flash-style. (unchanged from round 7)
// ---------------------------------------------------------------------------
__global__ __launch_bounds__(256) void attn_ctx_mfma(
    const u16* __restrict__ qh, const u16* __restrict__ kh,
    const u16* __restrict__ vt, u16* __restrict__ ctx,
    float* __restrict__ Zbuf)
{
  __shared__ __align__(16) u16 Ks[2][4096];   // 64 rows x 8 chunks x 8 bf16
  __shared__ __align__(16) u16 Vs[2][4096];
  __shared__ __align__(16) u16 Pl[4][1024];   // per-wave P[16][64], swizzled

  const int tid = threadIdx.x;
  const int wv = tid >> 6, lane = tid & 63, r = lane & 15, q4 = lane >> 4;
  const int b  = blockIdx.y;
  const int lw = blockIdx.x * 64 + wv * 16;
  const int n = b >> 4, h = b & 15;

  const u16* qbase = qh + (size_t)b * 65536;
  const char* kc = (const char*)(kh + (size_t)b * 65536);
  const char* vc = (const char*)(vt + (size_t)b * 65536);
  u16* P = Pl[wv];

  const int ls  = lane >> 3;               // row-in-octet 0..7
  const int swzb = ((lane & 7) ^ ls) << 4; // swizzled 16B-chunk byte offset
  const int iw  = wv * 2;
  const size_t klo = (size_t)iw * 1024 + (size_t)ls * 128 + swzb;   // K row = 128 B
  const size_t vlo = (size_t)iw * 16384 + (size_t)ls * 2048 + swzb; // V row = 2048 B

  const int rsw = r & 7;
  const int c0 = (q4 ^ rsw) << 3;          // u16 offset of logical chunk q4
  const int c1 = ((q4 ^ rsw) ^ 4) << 3;    // logical chunk q4+4

  short8 aq0 = *(const short8*)(qbase + (size_t)(lw + r) * 64 + q4 * 8);
  short8 aq1 = *(const short8*)(qbase + (size_t)(lw + r) * 64 + 32 + q4 * 8);

  f32x4 oc[4];
  #pragma unroll
  for (int ji = 0; ji < 4; ++ji) oc[ji] = (f32x4){0.f, 0.f, 0.f, 0.f};
  float z[4] = {0.f, 0.f, 0.f, 0.f};

  {
    const char* kp = kc + klo;
    const char* vp = vc + vlo;
    u16* kd = &Ks[0][iw * 512];
    u16* vd = &Vs[0][iw * 512];
    __builtin_amdgcn_global_load_lds(kp,          kd,       16, 0, 0);
    __builtin_amdgcn_global_load_lds(kp + 1024,   kd + 512, 16, 0, 0);
    __builtin_amdgcn_global_load_lds(vp,          vd,       16, 0, 0);
    __builtin_amdgcn_global_load_lds(vp + 16384,  vd + 512, 16, 0, 0);
  }

  for (int it = 0; it < 16; ++it) {
    const int cur = it & 1;
    __syncthreads();   // drains vmcnt -> Ks/Vs[cur] staged; prev-iter reads done
    const u16* Kb = Ks[cur];
    const u16* Vb = Vs[cur];

    f32x4 sc[4];
    #pragma unroll
    for (int ji = 0; ji < 4; ++ji) {
      const int row = (ji * 16 + r) * 64;
      short8 bk0 = *(const short8*)(Kb + row + c0);
      short8 bk1 = *(const short8*)(Kb + row + c1);
      f32x4 t = (f32x4){0.f, 0.f, 0.f, 0.f};
      t = __builtin_amdgcn_mfma_f32_16x16x32_bf16(aq0, bk0, t, 0, 0, 0);
      t = __builtin_amdgcn_mfma_f32_16x16x32_bf16(aq1, bk1, t, 0, 0, 0);
      sc[ji] = t;
    }

    if (it < 15) {
      const char* kp = kc + (size_t)(it + 1) * 8192 + klo;  // 64 rows * 128 B
      const char* vp = vc + (size_t)(it + 1) * 128  + vlo;  // 64 cols * 2 B
      u16* kd = &Ks[cur ^ 1][iw * 512];
      u16* vd = &Vs[cur ^ 1][iw * 512];
      __builtin_amdgcn_global_load_lds(kp,          kd,       16, 0, 0);
      __builtin_amdgcn_global_load_lds(kp + 1024,   kd + 512, 16, 0, 0);
      __builtin_amdgcn_global_load_lds(vp,          vd,       16, 0, 0);
      __builtin_amdgcn_global_load_lds(vp + 16384,  vd + 512, 16, 0, 0);
    }

    #pragma unroll
    for (int ji = 0; ji < 4; ++ji) {
      const int cw = ji * 2 + (r >> 3);   // logical 8-elt chunk of col ji*16+r
      #pragma unroll
      for (int rr = 0; rr < 4; ++rr) {
        float e = __expf(sc[ji][rr]);
        z[rr] += e;
        const int row = q4 * 4 + rr;
        P[row * 64 + ((cw ^ (row & 7)) << 3) + (r & 7)] = f2bf(e);
      }
    }
    asm volatile("s_waitcnt lgkmcnt(0)" ::: "memory");
    short8 ap0 = *(const short8*)(P + r * 64 + c0);
    short8 ap1 = *(const short8*)(P + r * 64 + c1);
    #pragma unroll
    for (int ji = 0; ji < 4; ++ji) {
      const int row = (ji * 16 + r) * 64;
      short8 bv0 = *(const short8*)(Vb + row + c0);
      short8 bv1 = *(const short8*)(Vb + row + c1);
      oc[ji] = __builtin_amdgcn_mfma_f32_16x16x32_bf16(ap0, bv0, oc[ji], 0, 0, 0);
      oc[ji] = __builtin_amdgcn_mfma_f32_16x16x32_bf16(ap1, bv1, oc[ji], 0, 0, 0);
    }
  }

  #pragma unroll
  for (int rr = 0; rr < 4; ++rr) {
    float zz = z[rr];
    zz += __shfl_xor(zz, 1);
    zz += __shfl_xor(zz, 2);
    zz += __shfl_xor(zz, 4);
    zz += __shfl_xor(zz, 8);
    z[rr] = zz;
  }

  #pragma unroll
  for (int rr = 0; rr < 4; ++rr) {
    float inv = 1.0f / z[rr];
    int l = lw + q4 * 4 + rr;
    u16* crow = ctx + ((size_t)l * 4 + n) * 1024 + h * 64;
    #pragma unroll
    for (int ji = 0; ji < 4; ++ji)
      crow[ji * 16 + r] = f2bf(oc[ji][rr] * inv);
    if (r == 0) Zbuf[(size_t)b * 1024 + l] = z[rr];
  }
}

// ---------------------------------------------------------------------------
// Kernel 3: head-averaged attention weights. (unchanged from round 7)
// ---------------------------------------------------------------------------
__global__ __launch_bounds__(256) void attn_w_mfma(
    const u16* __restrict__ qh, const u16* __restrict__ kh,
    const float* __restrict__ Zbuf, float* __restrict__ out_w)
{
  __shared__ __align__(16) u16 Kw[2][4096];
  __shared__ float invZ[16][64];

  const int tid = threadIdx.x;
  const int wv = tid >> 6, lane = tid & 63, r = lane & 15, q4 = lane >> 4;
  const int lt = blockIdx.x;
  const int st = blockIdx.y;
  const int n  = blockIdx.z;
  const int l0 = lt * 64;
  const int s0 = st * 64;
  const int lw = l0 + wv * 16;

  const char* khc = (const char*)kh + (size_t)n * 2097152;  // 16 heads * 128 KB

  const int ls  = lane >> 3;
  const int swzb = ((lane & 7) ^ ls) << 4;
  const int iw  = wv * 2;
  const size_t klo = (size_t)s0 * 128 + (size_t)iw * 1024 + (size_t)ls * 128 + swzb;

  const int rsw = r & 7;
  const int c0 = (q4 ^ rsw) << 3;
  const int c1 = ((q4 ^ rsw) ^ 4) << 3;

  for (int i = tid; i < 1024; i += 256) {
    int hh = i >> 6, row = i & 63;
    invZ[hh][row] = 1.0f / (Zbuf[(size_t)(n * 16 + hh) * 1024 + l0 + row] * 16.0f);
  }

  {
    const char* kp = khc + klo;
    u16* kd = &Kw[0][iw * 512];
    __builtin_amdgcn_global_load_lds(kp,        kd,       16, 0, 0);
    __builtin_amdgcn_global_load_lds(kp + 1024, kd + 512, 16, 0, 0);
  }
  const u16* q0 = qh + (size_t)(n * 16) * 65536;
  short8 aqc0 = *(const short8*)(q0 + (size_t)(lw + r) * 64 + q4 * 8);
  short8 aqc1 = *(const short8*)(q0 + (size_t)(lw + r) * 64 + 32 + q4 * 8);

  f32x4 wacc[4];
  #pragma unroll
  for (int ji = 0; ji < 4; ++ji) wacc[ji] = (f32x4){0.f, 0.f, 0.f, 0.f};

  for (int hh = 0; hh < 16; ++hh) {
    const int cur = hh & 1;
    __syncthreads();   // Kw[cur] staged (and invZ on first iter); prev reads done
    if (hh < 15) {
      const char* kp = khc + (size_t)(hh + 1) * 131072 + klo;
      u16* kd = &Kw[cur ^ 1][iw * 512];
      __builtin_amdgcn_global_load_lds(kp,        kd,       16, 0, 0);
      __builtin_amdgcn_global_load_lds(kp + 1024, kd + 512, 16, 0, 0);
    }
    const int hn = (hh < 15) ? hh + 1 : hh;
    const u16* qn = qh + (size_t)(n * 16 + hn) * 65536;
    short8 an0 = *(const short8*)(qn + (size_t)(lw + r) * 64 + q4 * 8);
    short8 an1 = *(const short8*)(qn + (size_t)(lw + r) * 64 + 32 + q4 * 8);

    const u16* Kb = Kw[cur];
    f32x4 sc[4];
    #pragma unroll
    for (int ji = 0; ji < 4; ++ji) {
      const int row = (ji * 16 + r) * 64;
      short8 bk0 = *(const short8*)(Kb + row + c0);
      short8 bk1 = *(const short8*)(Kb + row + c1);
      f32x4 t = (f32x4){0.f, 0.f, 0.f, 0.f};
      t = __builtin_amdgcn_mfma_f32_16x16x32_bf16(aqc0, bk0, t, 0, 0, 0);
      t = __builtin_amdgcn_mfma_f32_16x16x32_bf16(aqc1, bk1, t, 0, 0, 0);
      sc[ji] = t;
    }
    #pragma unroll
    for (int rr = 0; rr < 4; ++rr) {
      float iv = invZ[hh][wv * 16 + q4 * 4 + rr];
      #pragma unroll
      for (int ji = 0; ji < 4; ++ji)
        wacc[ji][rr] += __expf(sc[ji][rr]) * iv;
    }
    aqc0 = an0; aqc1 = an1;
  }

  #pragma unroll
  for (int ji = 0; ji < 4; ++ji)
    #pragma unroll
    for (int rr = 0; rr < 4; ++rr) {
      int row = lw + q4 * 4 + rr;
      int col = s0 + ji * 16 + r;
      out_w[(size_t)n * 1048576 + (size_t)row * 1024 + col] = wacc[ji][rr];
    }
}

// ---------------------------------------------------------------------------
// Kernel 4: output projection. (unchanged from round 9)
// ---------------------------------------------------------------------------
__global__ __launch_bounds__(256) void out_gemm(
    const u16* __restrict__ ctx, const u16* __restrict__ W,
    const float* __restrict__ bias, float* __restrict__ out)
{
  __shared__ __align__(16) u16 As[2][128 * 32];   // 8 KB per buffer
  __shared__ __align__(16) u16 Bs[2][64 * 32];    // 4 KB per buffer

  const int tid  = threadIdx.x;
  const int wave = tid >> 6;
  const int lane = tid & 63;
  const int r    = lane & 15;
  const int q4   = lane >> 4;
  const int wm   = wave >> 1;          // 0..1 (row half: 64 rows)
  const int wn   = wave & 1;           // 0..1 (col half: 32 cols)

  const int orig = blockIdx.y * 16 + blockIdx.x;
  const int nid  = (orig & 7) * 64 + (orig >> 3);
  const int mt   = nid >> 4;           // 0..31
  const int jt   = nid & 15;           // 0..15
  const int m0 = mt * 128;
  const int j0 = jt * 64;

  const int lrow = lane >> 2;
  const int lchk = ((lane & 3) ^ ((lane >> 3) & 3)) << 4;
  const char* Ac = (const char*)ctx;
  const char* Wc = (const char*)W;
  const int fchk = (q4 ^ ((r >> 1) & 3)) << 3;

  f32x4 acc[4][2];
  #pragma unroll
  for (int a = 0; a < 4; ++a)
    #pragma unroll
    for (int b = 0; b < 2; ++b)
      acc[a][b] = (f32x4){0.f, 0.f, 0.f, 0.f};

  auto STAGE = [&](int buf, int kt) {
    const int kbyte = kt * 64;
    #pragma unroll
    for (int i = 0; i < 2; ++i) {
      const int g = wave * 2 + i;      // A group 0..7
      __builtin_amdgcn_global_load_lds(
          (const u16*)(Ac + (size_t)(m0 + g * 16 + lrow) * 2048 + kbyte + lchk),
          &As[buf][g * 512], 16, 0, 0);
    }
    __builtin_amdgcn_global_load_lds(
        (const u16*)(Wc + (size_t)(j0 + wave * 16 + lrow) * 2048 + kbyte + lchk),
        &Bs[buf][wave * 512], 16, 0, 0);
  };

  STAGE(0, 0);
  for (int kt = 0; kt < 32; ++kt) {
    const int cur = kt & 1;
    __syncthreads();
    if (kt < 31) STAGE(cur ^ 1, kt + 1);

    short8 af[4], bf[2];
    #pragma unroll
    for (int mi = 0; mi < 4; ++mi)
      af[mi] = *(const short8*)(&As[cur][(wm * 64 + mi * 16 + r) * 32 + fchk]);
    #pragma unroll
    for (int ji = 0; ji < 2; ++ji)
      bf[ji] = *(const short8*)(&Bs[cur][(wn * 32 + ji * 16 + r) * 32 + fchk]);
    #pragma unroll
    for (int mi = 0; mi < 4; ++mi)
      #pragma unroll
      for (int ji = 0; ji < 2; ++ji)
        acc[mi][ji] = __builtin_amdgcn_mfma_f32_16x16x32_bf16(af[mi], bf[ji], acc[mi][ji], 0, 0, 0);
  }

  #pragma unroll
  for (int mi = 0; mi < 4; ++mi) {
    #pragma unroll
    for (int ji = 0; ji < 2; ++ji) {
      #pragma unroll
      for (int rr = 0; rr < 4; ++rr) {
        int m = m0 + wm * 64 + mi * 16 + q4 * 4 + rr;
        int j = j0 + wn * 32 + ji * 16 + r;
        out[(size_t)m * 1024 + j] = acc[mi][ji][rr] + bias[j];
      }
    }
  }
}

// ---------------------------------------------------------------------------
extern "C" void kernel_launch(void* const* d_in, const int* in_sizes, int n_in,
                              void* d_out, int out_size, void* d_ws, size_t ws_size,
                              hipStream_t stream) {
  const float* query = (const float*)d_in[0];
  const float* key   = (const float*)d_in[1];
  const float* value = (const float*)d_in[2];
  const float* W_in  = (const float*)d_in[3];
  const float* b_in  = (const float*)d_in[4];
  const float* W_out = (const float*)d_in[5];
  const float* b_out = (const float*)d_in[6];
  float* out = (float*)d_out;

  // ws (~64.3 MB): qb 8 | kb 8 | vb 8 | Wib 6 | Wob 2 | qh 8 | kh 8 | vt 8 | ctx 8 | Z .25
  u16* qb  = (u16*)d_ws;
  u16* kb  = qb  + (size_t)4194304;
  u16* vb  = kb  + (size_t)4194304;
  u16* Wib = vb  + (size_t)4194304;
  u16* Wob = Wib + (size_t)3145728;
  u16* qh  = Wob + (size_t)1048576;
  u16* kh  = qh  + (size_t)4194304;
  u16* vt  = kh  + (size_t)4194304;
  u16* ctx = vt  + (size_t)4194304;
  float* Zbuf = (float*)(ctx + (size_t)4194304);

  convert_bf16<<<dim3(512, 5), 256, 0, stream>>>(query, key, value, W_in, W_out,
                                                 qb, kb, vb, Wib, Wob);
  qkv_gemm<<<dim3(24, 32), 256, 0, stream>>>(qb, kb, vb, Wib, b_in, qh, kh, vt);
  attn_ctx_mfma<<<dim3(16, 64), 256, 0, stream>>>(qh, kh, vt, ctx, Zbuf);
  attn_w_mfma<<<dim3(16, 16, 4), 256, 0, stream>>>(qh, kh, Zbuf, out + (size_t)4194304);
  out_gemm<<<dim3(16, 32), 256, 0, stream>>>(ctx, Wob, b_out, out);
}

// Round 7
// 232.386 us; speedup vs baseline: 1.0577x; 1.0577x over previous
//
#include <hip/hip_runtime.h>

// MHA forward. L=S=1024, N=4, E=1024, H=16, hd=64, B=N*H=64, M=L*N=4096
// Inputs fp32, outputs fp32 (out0=attn_output 4.19M, out1=attn_weights 4.19M @+4194304).
// Round 13: r12 still raced (absmax 2.9e-2). Root cause = guide rule #18: hipcc
// sinks register-only MFMAs AND their compiler-inserted lgkmcnt waits past a
// memory-clobber asm s_barrier. So a wave could cross the barrier with its
// ds_reads of buffer (kt%3) still outstanding while a fast wave STAGEs (kt+3)
// into that same buffer -> intermittent WAR corruption. r10's __syncthreads was
// immune (intrinsic emits vmcnt(0) lgkmcnt(0) before s_barrier). Fix: fold
// lgkmcnt(0) into the pre-barrier counted wait in ONE asm blob:
//   s_waitcnt vmcnt(4) lgkmcnt(0); s_barrier   (final tile: vmcnt(0))
// -> wave's LDS reads provably complete before it can pass the barrier; global
// prefetch loads still stay in flight across barriers (the T4 win). Same fix in
// out_gemm. All else identical to r12/r10.
typedef unsigned short u16;
typedef __attribute__((ext_vector_type(8))) short short8;   // 8 bf16 (4 VGPRs)
typedef __attribute__((ext_vector_type(4))) float f32x4;    // MFMA accumulator

__device__ __forceinline__ u16 f2bf(float f) {  // RNE
  unsigned int i = __float_as_uint(f);
  i += 0x7fffu + ((i >> 16) & 1u);
  return (u16)(i >> 16);
}

__device__ __forceinline__ short8 cvt8(const float* p) {
  float4 a = ((const float4*)p)[0];
  float4 b = ((const float4*)p)[1];
  short8 r;
  r[0] = (short)f2bf(a.x); r[1] = (short)f2bf(a.y);
  r[2] = (short)f2bf(a.z); r[3] = (short)f2bf(a.w);
  r[4] = (short)f2bf(b.x); r[5] = (short)f2bf(b.y);
  r[6] = (short)f2bf(b.z); r[7] = (short)f2bf(b.w);
  return r;
}

// ---------------------------------------------------------------------------
// Kernel 0: one-shot fp32 -> bf16 conversion of q/k/v/W_in/W_out. (unchanged)
// ---------------------------------------------------------------------------
__global__ __launch_bounds__(256) void convert_bf16(
    const float* __restrict__ q, const float* __restrict__ k,
    const float* __restrict__ v, const float* __restrict__ Wi,
    const float* __restrict__ Wo,
    u16* __restrict__ qb, u16* __restrict__ kb, u16* __restrict__ vb,
    u16* __restrict__ Wib, u16* __restrict__ Wob)
{
  const float* src; u16* dst; int len8;
  switch (blockIdx.y) {
    case 0:  src = q;  dst = qb;  len8 = 524288; break;  // 4M elts
    case 1:  src = k;  dst = kb;  len8 = 524288; break;
    case 2:  src = v;  dst = vb;  len8 = 524288; break;
    case 3:  src = Wi; dst = Wib; len8 = 393216; break;  // 3M elts
    default: src = Wo; dst = Wob; len8 = 131072; break;  // 1M elts
  }
  int stride = gridDim.x * 256;
  for (int i = blockIdx.x * 256 + threadIdx.x; i < len8; i += stride)
    *(short8*)(dst + (size_t)i * 8) = cvt8(src + (size_t)i * 8);
}

// ---------------------------------------------------------------------------
// Kernel 1: packed QKV projection. 128x128 tile, BK=32, 3-buffer counted-vmcnt
// pipeline (stage kt+2; steady wait vmcnt(4)+lgkmcnt(0)+s_barrier; final tile
// vmcnt(0)). Coalesced LDS epilogue. C = X.W^T + bias; M=4096,K=1024,J=3072.
// ---------------------------------------------------------------------------
__global__ __launch_bounds__(256) void qkv_gemm(
    const u16* __restrict__ qb, const u16* __restrict__ kb,
    const u16* __restrict__ vb, const u16* __restrict__ W,
    const float* __restrict__ bias,
    u16* __restrict__ qh, u16* __restrict__ kh, u16* __restrict__ vt)
{
  // 48 KB: A bufs [0,12288), B bufs [12288,24576); epilogue reuses [0,16384)
  __shared__ __align__(16) u16 SH[24576];

  const int tid  = threadIdx.x;
  const int wave = tid >> 6;
  const int lane = tid & 63;
  const int r    = lane & 15;
  const int q4   = lane >> 4;
  const int wm   = wave >> 1;          // 0..1  (row quadrant)
  const int wn   = wave & 1;           // 0..1  (col quadrant)

  // XCD-chunked swizzle: one XCD covers 4 m-tiles x all j-tiles.
  const int orig = blockIdx.y * 24 + blockIdx.x;
  const int nid  = (orig & 7) * 96 + (orig >> 3);
  const int mt   = nid / 24;           // 0..31
  const int jt   = nid - mt * 24;      // 0..23
  const int src  = jt >> 3;            // 0=q, 1=k, 2=v
  const u16* X = (src == 0) ? qb : (src == 1) ? kb : vb;
  const int m0 = mt * 128;
  const int j0 = jt * 128;

  // staging: per gload_lds instr a wave covers 16 rows x 64B (1KB).
  const int lrow = lane >> 2;
  const int lchk = ((lane & 3) ^ ((lane >> 3) & 3)) << 4;   // byte offset
  const char* Xc = (const char*)X;
  const char* Wc = (const char*)W;

  // fragment-read: logical chunk q4 of row (..+r) lives at phys q4^((r>>1)&3)
  const int fchk = (q4 ^ ((r >> 1) & 3)) << 3;              // u16 offset

  f32x4 acc[4][4];
  #pragma unroll
  for (int a = 0; a < 4; ++a)
    #pragma unroll
    for (int b = 0; b < 4; ++b)
      acc[a][b] = (f32x4){0.f, 0.f, 0.f, 0.f};

  auto STAGE = [&](int buf, int kt) {   // 4 gload_lds per wave
    const int kbyte = kt * 64;
    u16* Ad = SH + buf * 4096;
    u16* Bd = SH + 12288 + buf * 4096;
    #pragma unroll
    for (int i = 0; i < 2; ++i) {
      const int g = wave * 2 + i;      // 16-row group 0..7
      __builtin_amdgcn_global_load_lds(
          (const u16*)(Xc + (size_t)(m0 + g * 16 + lrow) * 2048 + kbyte + lchk),
          Ad + g * 512, 16, 0, 0);
      __builtin_amdgcn_global_load_lds(
          (const u16*)(Wc + (size_t)(j0 + g * 16 + lrow) * 2048 + kbyte + lchk),
          Bd + g * 512, 16, 0, 0);
    }
  };

  auto COMPUTE = [&](int cb) {
    const u16* As = SH + cb * 4096;
    const u16* Bs = SH + 12288 + cb * 4096;
    short8 af[4], bf[4];
    #pragma unroll
    for (int mi = 0; mi < 4; ++mi)
      af[mi] = *(const short8*)(&As[(wm * 64 + mi * 16 + r) * 32 + fchk]);
    #pragma unroll
    for (int ji = 0; ji < 4; ++ji)
      bf[ji] = *(const short8*)(&Bs[(wn * 64 + ji * 16 + r) * 32 + fchk]);
    #pragma unroll
    for (int mi = 0; mi < 4; ++mi)
      #pragma unroll
      for (int ji = 0; ji < 4; ++ji)
        acc[mi][ji] = __builtin_amdgcn_mfma_f32_16x16x32_bf16(af[mi], bf[ji], acc[mi][ji], 0, 0, 0);
  };

  STAGE(0, 0);
  STAGE(1, 1);
  int cb = 0;                          // kt % 3
  for (int kt = 0; kt < 31; ++kt) {
    // vmcnt(4): own STAGE(kt) drained (STAGE(kt+1) stays in flight).
    // lgkmcnt(0): own ds_reads of COMPUTE(kt-1) complete BEFORE the barrier --
    // closes the rule-#18 sink race (MFMA+wait moved past asm barrier).
    asm volatile("s_waitcnt vmcnt(4) lgkmcnt(0)\n\ts_barrier" ::: "memory");
    if (kt < 30) {
      int nb = cb + 2; if (nb >= 3) nb -= 3;
      STAGE(nb, kt + 2);
    }
    COMPUTE(cb);
    if (++cb == 3) cb = 0;
  }
  // FINAL tile (kt=31): only STAGE(31)'s 4 loads outstanding -> full drain.
  asm volatile("s_waitcnt vmcnt(0) lgkmcnt(0)\n\ts_barrier" ::: "memory");
  COMPUTE(cb);

  // ---- coalesced epilogue: acc -> LDS (permuted+swizzled) -> short8 stores.
  //   local m = wm*64+mi*16+q4*4+rr -> tt = wm*16+mi*4+q4 (t = mt*32+tt), n = rr
  //   local j = wn*64+ji*16+r       -> hq = j>>6 (h = h0+hq), d = j&63
  __syncthreads();                     // all waves done with K-loop LDS
  const int h0 = (j0 & 1023) >> 6;
  const int t0 = mt * 32;
  if (src < 2) {
    // LDS layout [n][hq][tt][d], d-chunks XOR-swizzled by tt&7
    #pragma unroll
    for (int mi = 0; mi < 4; ++mi) {
      const int tt = wm * 16 + mi * 4 + q4;
      #pragma unroll
      for (int ji = 0; ji < 4; ++ji) {
        const int jj = wn * 64 + ji * 16 + r;
        const int dd = jj & 63, hq = jj >> 6;
        const int cs = (((dd >> 3) ^ (tt & 7)) << 3) + (dd & 7);
        #pragma unroll
        for (int rr = 0; rr < 4; ++rr) {
          float v = acc[mi][ji][rr] + bias[j0 + jj];
          SH[((rr * 2 + hq) * 32 + tt) * 64 + cs] =
              (src == 0) ? f2bf(v * 0.125f) : f2bf(v);
        }
      }
    }
    __syncthreads();
    u16* dst = (src == 0) ? qh : kh;
    #pragma unroll
    for (int c = 0; c < 8; ++c) {
      const int cid = c * 256 + tid;   // consecutive lanes -> consecutive chunks
      const int nn = cid >> 9, hq = (cid >> 8) & 1, tt = (cid >> 3) & 31, dc = cid & 7;
      short8 vv = *(const short8*)(SH + ((nn * 2 + hq) * 32 + tt) * 64 +
                                   ((dc ^ (tt & 7)) << 3));
      *(short8*)(dst + (size_t)(nn * 16 + h0 + hq) * 65536 +
                 (size_t)(t0 + tt) * 64 + dc * 8) = vv;
    }
  } else {
    // LDS layout [bbv=n*2+hq][d][t] (t fast, 32 elts), t-chunks XOR'd by d&3
    #pragma unroll
    for (int mi = 0; mi < 4; ++mi) {
      const int tt = wm * 16 + mi * 4 + q4;
      const int tc = tt >> 3, toff = tt & 7;
      #pragma unroll
      for (int ji = 0; ji < 4; ++ji) {
        const int jj = wn * 64 + ji * 16 + r;
        const int dd = jj & 63, hq = jj >> 6;
        #pragma unroll
        for (int rr = 0; rr < 4; ++rr) {
          float v = acc[mi][ji][rr] + bias[j0 + jj];
          SH[((rr * 2 + hq) * 64 + dd) * 32 + ((tc ^ (dd & 3)) << 3) + toff] = f2bf(v);
        }
      }
    }
    __syncthreads();
    #pragma unroll
    for (int c = 0; c < 8; ++c) {
      const int cid = c * 256 + tid;
      const int bbv = cid >> 8, dd = (cid >> 2) & 63, tc = cid & 3;
      short8 vv = *(const short8*)(SH + (bbv * 64 + dd) * 32 +
                                   ((tc ^ (dd & 3)) << 3));
      const int bb = (bbv >> 1) * 16 + h0 + (bbv & 1);
      *(short8*)(vt + (size_t)bb * 65536 + (size_t)dd * 1024 + t0 + tc * 8) = vv;
    }
  }
}

// ---------------------------------------------------------------------------
// Kernel 2: attention context, MFMA flash-style. (unchanged from round 7)
// ---------------------------------------------------------------------------
__global__ __launch_bounds__(256) void attn_ctx_mfma(
    const u16* __restrict__ qh, const u16* __restrict__ kh,
    const u16* __restrict__ vt, u16* __restrict__ ctx,
    float* __restrict__ Zbuf)
{
  __shared__ __align__(16) u16 Ks[2][4096];   // 64 rows x 8 chunks x 8 bf16
  __shared__ __align__(16) u16 Vs[2][4096];
  __shared__ __align__(16) u16 Pl[4][1024];   // per-wave P[16][64], swizzled

  const int tid = threadIdx.x;
  const int wv = tid >> 6, lane = tid & 63, r = lane & 15, q4 = lane >> 4;
  const int b  = blockIdx.y;
  const int lw = blockIdx.x * 64 + wv * 16;
  const int n = b >> 4, h = b & 15;

  const u16* qbase = qh + (size_t)b * 65536;
  const char* kc = (const char*)(kh + (size_t)b * 65536);
  const char* vc = (const char*)(vt + (size_t)b * 65536);
  u16* P = Pl[wv];

  const int ls  = lane >> 3;               // row-in-octet 0..7
  const int swzb = ((lane & 7) ^ ls) << 4; // swizzled 16B-chunk byte offset
  const int iw  = wv * 2;
  const size_t klo = (size_t)iw * 1024 + (size_t)ls * 128 + swzb;   // K row = 128 B
  const size_t vlo = (size_t)iw * 16384 + (size_t)ls * 2048 + swzb; // V row = 2048 B

  const int rsw = r & 7;
  const int c0 = (q4 ^ rsw) << 3;          // u16 offset of logical chunk q4
  const int c1 = ((q4 ^ rsw) ^ 4) << 3;    // logical chunk q4+4

  short8 aq0 = *(const short8*)(qbase + (size_t)(lw + r) * 64 + q4 * 8);
  short8 aq1 = *(const short8*)(qbase + (size_t)(lw + r) * 64 + 32 + q4 * 8);

  f32x4 oc[4];
  #pragma unroll
  for (int ji = 0; ji < 4; ++ji) oc[ji] = (f32x4){0.f, 0.f, 0.f, 0.f};
  float z[4] = {0.f, 0.f, 0.f, 0.f};

  {
    const char* kp = kc + klo;
    const char* vp = vc + vlo;
    u16* kd = &Ks[0][iw * 512];
    u16* vd = &Vs[0][iw * 512];
    __builtin_amdgcn_global_load_lds(kp,          kd,       16, 0, 0);
    __builtin_amdgcn_global_load_lds(kp + 1024,   kd + 512, 16, 0, 0);
    __builtin_amdgcn_global_load_lds(vp,          vd,       16, 0, 0);
    __builtin_amdgcn_global_load_lds(vp + 16384,  vd + 512, 16, 0, 0);
  }

  for (int it = 0; it < 16; ++it) {
    const int cur = it & 1;
    __syncthreads();   // drains vmcnt -> Ks/Vs[cur] staged; prev-iter reads done
    const u16* Kb = Ks[cur];
    const u16* Vb = Vs[cur];

    f32x4 sc[4];
    #pragma unroll
    for (int ji = 0; ji < 4; ++ji) {
      const int row = (ji * 16 + r) * 64;
      short8 bk0 = *(const short8*)(Kb + row + c0);
      short8 bk1 = *(const short8*)(Kb + row + c1);
      f32x4 t = (f32x4){0.f, 0.f, 0.f, 0.f};
      t = __builtin_amdgcn_mfma_f32_16x16x32_bf16(aq0, bk0, t, 0, 0, 0);
      t = __builtin_amdgcn_mfma_f32_16x16x32_bf16(aq1, bk1, t, 0, 0, 0);
      sc[ji] = t;
    }

    if (it < 15) {
      const char* kp = kc + (size_t)(it + 1) * 8192 + klo;  // 64 rows * 128 B
      const char* vp = vc + (size_t)(it + 1) * 128  + vlo;  // 64 cols * 2 B
      u16* kd = &Ks[cur ^ 1][iw * 512];
      u16* vd = &Vs[cur ^ 1][iw * 512];
      __builtin_amdgcn_global_load_lds(kp,          kd,       16, 0, 0);
      __builtin_amdgcn_global_load_lds(kp + 1024,   kd + 512, 16, 0, 0);
      __builtin_amdgcn_global_load_lds(vp,          vd,       16, 0, 0);
      __builtin_amdgcn_global_load_lds(vp + 16384,  vd + 512, 16, 0, 0);
    }

    #pragma unroll
    for (int ji = 0; ji < 4; ++ji) {
      const int cw = ji * 2 + (r >> 3);   // logical 8-elt chunk of col ji*16+r
      #pragma unroll
      for (int rr = 0; rr < 4; ++rr) {
        float e = __expf(sc[ji][rr]);
        z[rr] += e;
        const int row = q4 * 4 + rr;
        P[row * 64 + ((cw ^ (row & 7)) << 3) + (r & 7)] = f2bf(e);
      }
    }
    asm volatile("s_waitcnt lgkmcnt(0)" ::: "memory");
    short8 ap0 = *(const short8*)(P + r * 64 + c0);
    short8 ap1 = *(const short8*)(P + r * 64 + c1);
    #pragma unroll
    for (int ji = 0; ji < 4; ++ji) {
      const int row = (ji * 16 + r) * 64;
      short8 bv0 = *(const short8*)(Vb + row + c0);
      short8 bv1 = *(const short8*)(Vb + row + c1);
      oc[ji] = __builtin_amdgcn_mfma_f32_16x16x32_bf16(ap0, bv0, oc[ji], 0, 0, 0);
      oc[ji] = __builtin_amdgcn_mfma_f32_16x16x32_bf16(ap1, bv1, oc[ji], 0, 0, 0);
    }
  }

  #pragma unroll
  for (int rr = 0; rr < 4; ++rr) {
    float zz = z[rr];
    zz += __shfl_xor(zz, 1);
    zz += __shfl_xor(zz, 2);
    zz += __shfl_xor(zz, 4);
    zz += __shfl_xor(zz, 8);
    z[rr] = zz;
  }

  #pragma unroll
  for (int rr = 0; rr < 4; ++rr) {
    float inv = 1.0f / z[rr];
    int l = lw + q4 * 4 + rr;
    u16* crow = ctx + ((size_t)l * 4 + n) * 1024 + h * 64;
    #pragma unroll
    for (int ji = 0; ji < 4; ++ji)
      crow[ji * 16 + r] = f2bf(oc[ji][rr] * inv);
    if (r == 0) Zbuf[(size_t)b * 1024 + l] = z[rr];
  }
}

// ---------------------------------------------------------------------------
// Kernel 3: head-averaged attention weights. (unchanged from round 7)
// ---------------------------------------------------------------------------
__global__ __launch_bounds__(256) void attn_w_mfma(
    const u16* __restrict__ qh, const u16* __restrict__ kh,
    const float* __restrict__ Zbuf, float* __restrict__ out_w)
{
  __shared__ __align__(16) u16 Kw[2][4096];
  __shared__ float invZ[16][64];

  const int tid = threadIdx.x;
  const int wv = tid >> 6, lane = tid & 63, r = lane & 15, q4 = lane >> 4;
  const int lt = blockIdx.x;
  const int st = blockIdx.y;
  const int n  = blockIdx.z;
  const int l0 = lt * 64;
  const int s0 = st * 64;
  const int lw = l0 + wv * 16;

  const char* khc = (const char*)kh + (size_t)n * 2097152;  // 16 heads * 128 KB

  const int ls  = lane >> 3;
  const int swzb = ((lane & 7) ^ ls) << 4;
  const int iw  = wv * 2;
  const size_t klo = (size_t)s0 * 128 + (size_t)iw * 1024 + (size_t)ls * 128 + swzb;

  const int rsw = r & 7;
  const int c0 = (q4 ^ rsw) << 3;
  const int c1 = ((q4 ^ rsw) ^ 4) << 3;

  for (int i = tid; i < 1024; i += 256) {
    int hh = i >> 6, row = i & 63;
    invZ[hh][row] = 1.0f / (Zbuf[(size_t)(n * 16 + hh) * 1024 + l0 + row] * 16.0f);
  }

  {
    const char* kp = khc + klo;
    u16* kd = &Kw[0][iw * 512];
    __builtin_amdgcn_global_load_lds(kp,        kd,       16, 0, 0);
    __builtin_amdgcn_global_load_lds(kp + 1024, kd + 512, 16, 0, 0);
  }
  const u16* q0 = qh + (size_t)(n * 16) * 65536;
  short8 aqc0 = *(const short8*)(q0 + (size_t)(lw + r) * 64 + q4 * 8);
  short8 aqc1 = *(const short8*)(q0 + (size_t)(lw + r) * 64 + 32 + q4 * 8);

  f32x4 wacc[4];
  #pragma unroll
  for (int ji = 0; ji < 4; ++ji) wacc[ji] = (f32x4){0.f, 0.f, 0.f, 0.f};

  for (int hh = 0; hh < 16; ++hh) {
    const int cur = hh & 1;
    __syncthreads();   // Kw[cur] staged (and invZ on first iter); prev reads done
    if (hh < 15) {
      const char* kp = khc + (size_t)(hh + 1) * 131072 + klo;
      u16* kd = &Kw[cur ^ 1][iw * 512];
      __builtin_amdgcn_global_load_lds(kp,        kd,       16, 0, 0);
      __builtin_amdgcn_global_load_lds(kp + 1024, kd + 512, 16, 0, 0);
    }
    const int hn = (hh < 15) ? hh + 1 : hh;
    const u16* qn = qh + (size_t)(n * 16 + hn) * 65536;
    short8 an0 = *(const short8*)(qn + (size_t)(lw + r) * 64 + q4 * 8);
    short8 an1 = *(const short8*)(qn + (size_t)(lw + r) * 64 + 32 + q4 * 8);

    const u16* Kb = Kw[cur];
    f32x4 sc[4];
    #pragma unroll
    for (int ji = 0; ji < 4; ++ji) {
      const int row = (ji * 16 + r) * 64;
      short8 bk0 = *(const short8*)(Kb + row + c0);
      short8 bk1 = *(const short8*)(Kb + row + c1);
      f32x4 t = (f32x4){0.f, 0.f, 0.f, 0.f};
      t = __builtin_amdgcn_mfma_f32_16x16x32_bf16(aqc0, bk0, t, 0, 0, 0);
      t = __builtin_amdgcn_mfma_f32_16x16x32_bf16(aqc1, bk1, t, 0, 0, 0);
      sc[ji] = t;
    }
    #pragma unroll
    for (int rr = 0; rr < 4; ++rr) {
      float iv = invZ[hh][wv * 16 + q4 * 4 + rr];
      #pragma unroll
      for (int ji = 0; ji < 4; ++ji)
        wacc[ji][rr] += __expf(sc[ji][rr]) * iv;
    }
    aqc0 = an0; aqc1 = an1;
  }

  #pragma unroll
  for (int ji = 0; ji < 4; ++ji)
    #pragma unroll
    for (int rr = 0; rr < 4; ++rr) {
      int row = lw + q4 * 4 + rr;
      int col = s0 + ji * 16 + r;
      out_w[(size_t)n * 1048576 + (size_t)row * 1024 + col] = wacc[ji][rr];
    }
}

// ---------------------------------------------------------------------------
// Kernel 4: output projection. 128(M)x64(J) tile, BK=32, 3-buffer counted-
// vmcnt pipeline (steady vmcnt(3)+lgkmcnt(0); final vmcnt(0)). 36KB LDS.
// ctx/Wob bf16 in, fp32 out. M=4096, K=1024, J=1024.
// ---------------------------------------------------------------------------
__global__ __launch_bounds__(256) void out_gemm(
    const u16* __restrict__ ctx, const u16* __restrict__ W,
    const float* __restrict__ bias, float* __restrict__ out)
{
  // A bufs [0,12288), B bufs [12288,18432)
  __shared__ __align__(16) u16 SH[18432];

  const int tid  = threadIdx.x;
  const int wave = tid >> 6;
  const int lane = tid & 63;
  const int r    = lane & 15;
  const int q4   = lane >> 4;
  const int wm   = wave >> 1;          // 0..1 (row half: 64 rows)
  const int wn   = wave & 1;           // 0..1 (col half: 32 cols)

  const int orig = blockIdx.y * 16 + blockIdx.x;
  const int nid  = (orig & 7) * 64 + (orig >> 3);
  const int mt   = nid >> 4;           // 0..31
  const int jt   = nid & 15;           // 0..15
  const int m0 = mt * 128;
  const int j0 = jt * 64;

  const int lrow = lane >> 2;
  const int lchk = ((lane & 3) ^ ((lane >> 3) & 3)) << 4;
  const char* Ac = (const char*)ctx;
  const char* Wc = (const char*)W;
  const int fchk = (q4 ^ ((r >> 1) & 3)) << 3;

  f32x4 acc[4][2];
  #pragma unroll
  for (int a = 0; a < 4; ++a)
    #pragma unroll
    for (int b = 0; b < 2; ++b)
      acc[a][b] = (f32x4){0.f, 0.f, 0.f, 0.f};

  auto STAGE = [&](int buf, int kt) {   // 3 gload_lds per wave
    const int kbyte = kt * 64;
    u16* Ad = SH + buf * 4096;
    u16* Bd = SH + 12288 + buf * 2048;
    #pragma unroll
    for (int i = 0; i < 2; ++i) {
      const int g = wave * 2 + i;      // A group 0..7
      __builtin_amdgcn_global_load_lds(
          (const u16*)(Ac + (size_t)(m0 + g * 16 + lrow) * 2048 + kbyte + lchk),
          Ad + g * 512, 16, 0, 0);
    }
    __builtin_amdgcn_global_load_lds(
        (const u16*)(Wc + (size_t)(j0 + wave * 16 + lrow) * 2048 + kbyte + lchk),
        Bd + wave * 512, 16, 0, 0);
  };

  auto COMPUTE = [&](int cb) {
    const u16* As = SH + cb * 4096;
    const u16* Bs = SH + 12288 + cb * 2048;
    short8 af[4], bf[2];
    #pragma unroll
    for (int mi = 0; mi < 4; ++mi)
      af[mi] = *(const short8*)(&As[(wm * 64 + mi * 16 + r) * 32 + fchk]);
    #pragma unroll
    for (int ji = 0; ji < 2; ++ji)
      bf[ji] = *(const short8*)(&Bs[(wn * 32 + ji * 16 + r) * 32 + fchk]);
    #pragma unroll
    for (int mi = 0; mi < 4; ++mi)
      #pragma unroll
      for (int ji = 0; ji < 2; ++ji)
        acc[mi][ji] = __builtin_amdgcn_mfma_f32_16x16x32_bf16(af[mi], bf[ji], acc[mi][ji], 0, 0, 0);
  };

  STAGE(0, 0);
  STAGE(1, 1);
  int cb = 0;
  for (int kt = 0; kt < 31; ++kt) {
    asm volatile("s_waitcnt vmcnt(3) lgkmcnt(0)\n\ts_barrier" ::: "memory");
    if (kt < 30) {
      int nb = cb + 2; if (nb >= 3) nb -= 3;
      STAGE(nb, kt + 2);
    }
    COMPUTE(cb);
    if (++cb == 3) cb = 0;
  }
  // FINAL tile: full drain.
  asm volatile("s_waitcnt vmcnt(0) lgkmcnt(0)\n\ts_barrier" ::: "memory");
  COMPUTE(cb);

  #pragma unroll
  for (int mi = 0; mi < 4; ++mi) {
    #pragma unroll
    for (int ji = 0; ji < 2; ++ji) {
      #pragma unroll
      for (int rr = 0; rr < 4; ++rr) {
        int m = m0 + wm * 64 + mi * 16 + q4 * 4 + rr;
        int j = j0 + wn * 32 + ji * 16 + r;
        out[(size_t)m * 1024 + j] = acc[mi][ji][rr] + bias[j];
      }
    }
  }
}

// ---------------------------------------------------------------------------
extern "C" void kernel_launch(void* const* d_in, const int* in_sizes, int n_in,
                              void* d_out, int out_size, void* d_ws, size_t ws_size,
                              hipStream_t stream) {
  const float* query = (const float*)d_in[0];
  const float* key   = (const float*)d_in[1];
  const float* value = (const float*)d_in[2];
  const float* W_in  = (const float*)d_in[3];
  const float* b_in  = (const float*)d_in[4];
  const float* W_out = (const float*)d_in[5];
  const float* b_out = (const float*)d_in[6];
  float* out = (float*)d_out;

  // ws (~64.3 MB): qb 8 | kb 8 | vb 8 | Wib 6 | Wob 2 | qh 8 | kh 8 | vt 8 | ctx 8 | Z .25
  u16* qb  = (u16*)d_ws;
  u16* kb  = qb  + (size_t)4194304;
  u16* vb  = kb  + (size_t)4194304;
  u16* Wib = vb  + (size_t)4194304;
  u16* Wob = Wib + (size_t)3145728;
  u16* qh  = Wob + (size_t)1048576;
  u16* kh  = qh  + (size_t)4194304;
  u16* vt  = kh  + (size_t)4194304;
  u16* ctx = vt  + (size_t)4194304;
  float* Zbuf = (float*)(ctx + (size_t)4194304);

  convert_bf16<<<dim3(512, 5), 256, 0, stream>>>(query, key, value, W_in, W_out,
                                                 qb, kb, vb, Wib, Wob);
  qkv_gemm<<<dim3(24, 32), 256, 0, stream>>>(qb, kb, vb, Wib, b_in, qh, kh, vt);
  attn_ctx_mfma<<<dim3(16, 64), 256, 0, stream>>>(qh, kh, vt, ctx, Zbuf);
  attn_w_mfma<<<dim3(16, 16, 4), 256, 0, stream>>>(qh, kh, Zbuf, out + (size_t)4194304);
  out_gemm<<<dim3(16, 32), 256, 0, stream>>>(ctx, Wob, b_out, out);
}

// Round 9
// 224.583 us; speedup vs baseline: 1.0944x; 1.0347x over previous
//
#include <hip/hip_runtime.h>

// MHA forward. L=S=1024, N=4, E=1024, H=16, hd=64, B=N*H=64, M=L*N=4096
// Inputs fp32, outputs fp32 (out0=attn_output 4.19M, out1=attn_weights 4.19M @+4194304).
// Round 15: r14's ds_read_b64_tr_b16 P-transpose was wrong (absmax 0.39) -- the
// HW tr-read layout (m156: per-16-lane-group subtile pattern) doesn't match the
// flat P_t[64][16] I assumed. REVERT attn_ctx to the r13 verified scalar
// P-roundtrip. Keep ONLY the tail fusion (attn_w + out_gemm in one 1536-block
// launch, 36KB LDS overlay) as the single delta vs r13 -- independent work,
// removes one ~10us dispatch and overlaps the two tails.
// convert/qkv unchanged from r13 (verified).
typedef unsigned short u16;
typedef __attribute__((ext_vector_type(8))) short short8;   // 8 bf16 (4 VGPRs)
typedef __attribute__((ext_vector_type(4))) float f32x4;    // MFMA accumulator

__device__ __forceinline__ u16 f2bf(float f) {  // RNE
  unsigned int i = __float_as_uint(f);
  i += 0x7fffu + ((i >> 16) & 1u);
  return (u16)(i >> 16);
}

__device__ __forceinline__ short8 cvt8(const float* p) {
  float4 a = ((const float4*)p)[0];
  float4 b = ((const float4*)p)[1];
  short8 r;
  r[0] = (short)f2bf(a.x); r[1] = (short)f2bf(a.y);
  r[2] = (short)f2bf(a.z); r[3] = (short)f2bf(a.w);
  r[4] = (short)f2bf(b.x); r[5] = (short)f2bf(b.y);
  r[6] = (short)f2bf(b.z); r[7] = (short)f2bf(b.w);
  return r;
}

// ---------------------------------------------------------------------------
// Kernel 0: one-shot fp32 -> bf16 conversion of q/k/v/W_in/W_out. (unchanged)
// ---------------------------------------------------------------------------
__global__ __launch_bounds__(256) void convert_bf16(
    const float* __restrict__ q, const float* __restrict__ k,
    const float* __restrict__ v, const float* __restrict__ Wi,
    const float* __restrict__ Wo,
    u16* __restrict__ qb, u16* __restrict__ kb, u16* __restrict__ vb,
    u16* __restrict__ Wib, u16* __restrict__ Wob)
{
  const float* src; u16* dst; int len8;
  switch (blockIdx.y) {
    case 0:  src = q;  dst = qb;  len8 = 524288; break;  // 4M elts
    case 1:  src = k;  dst = kb;  len8 = 524288; break;
    case 2:  src = v;  dst = vb;  len8 = 524288; break;
    case 3:  src = Wi; dst = Wib; len8 = 393216; break;  // 3M elts
    default: src = Wo; dst = Wob; len8 = 131072; break;  // 1M elts
  }
  int stride = gridDim.x * 256;
  for (int i = blockIdx.x * 256 + threadIdx.x; i < len8; i += stride)
    *(short8*)(dst + (size_t)i * 8) = cvt8(src + (size_t)i * 8);
}

// ---------------------------------------------------------------------------
// Kernel 1: packed QKV projection. (unchanged from r13 -- verified)
// 128x128 tile, BK=32, 3-buffer counted-vmcnt pipeline, coalesced epilogue.
// ---------------------------------------------------------------------------
__global__ __launch_bounds__(256) void qkv_gemm(
    const u16* __restrict__ qb, const u16* __restrict__ kb,
    const u16* __restrict__ vb, const u16* __restrict__ W,
    const float* __restrict__ bias,
    u16* __restrict__ qh, u16* __restrict__ kh, u16* __restrict__ vt)
{
  __shared__ __align__(16) u16 SH[24576];

  const int tid  = threadIdx.x;
  const int wave = tid >> 6;
  const int lane = tid & 63;
  const int r    = lane & 15;
  const int q4   = lane >> 4;
  const int wm   = wave >> 1;
  const int wn   = wave & 1;

  const int orig = blockIdx.y * 24 + blockIdx.x;
  const int nid  = (orig & 7) * 96 + (orig >> 3);
  const int mt   = nid / 24;
  const int jt   = nid - mt * 24;
  const int src  = jt >> 3;
  const u16* X = (src == 0) ? qb : (src == 1) ? kb : vb;
  const int m0 = mt * 128;
  const int j0 = jt * 128;

  const int lrow = lane >> 2;
  const int lchk = ((lane & 3) ^ ((lane >> 3) & 3)) << 4;
  const char* Xc = (const char*)X;
  const char* Wc = (const char*)W;
  const int fchk = (q4 ^ ((r >> 1) & 3)) << 3;

  f32x4 acc[4][4];
  #pragma unroll
  for (int a = 0; a < 4; ++a)
    #pragma unroll
    for (int b = 0; b < 4; ++b)
      acc[a][b] = (f32x4){0.f, 0.f, 0.f, 0.f};

  auto STAGE = [&](int buf, int kt) {   // 4 gload_lds per wave
    const int kbyte = kt * 64;
    u16* Ad = SH + buf * 4096;
    u16* Bd = SH + 12288 + buf * 4096;
    #pragma unroll
    for (int i = 0; i < 2; ++i) {
      const int g = wave * 2 + i;
      __builtin_amdgcn_global_load_lds(
          (const u16*)(Xc + (size_t)(m0 + g * 16 + lrow) * 2048 + kbyte + lchk),
          Ad + g * 512, 16, 0, 0);
      __builtin_amdgcn_global_load_lds(
          (const u16*)(Wc + (size_t)(j0 + g * 16 + lrow) * 2048 + kbyte + lchk),
          Bd + g * 512, 16, 0, 0);
    }
  };

  auto COMPUTE = [&](int cb) {
    const u16* As = SH + cb * 4096;
    const u16* Bs = SH + 12288 + cb * 4096;
    short8 af[4], bf[4];
    #pragma unroll
    for (int mi = 0; mi < 4; ++mi)
      af[mi] = *(const short8*)(&As[(wm * 64 + mi * 16 + r) * 32 + fchk]);
    #pragma unroll
    for (int ji = 0; ji < 4; ++ji)
      bf[ji] = *(const short8*)(&Bs[(wn * 64 + ji * 16 + r) * 32 + fchk]);
    #pragma unroll
    for (int mi = 0; mi < 4; ++mi)
      #pragma unroll
      for (int ji = 0; ji < 4; ++ji)
        acc[mi][ji] = __builtin_amdgcn_mfma_f32_16x16x32_bf16(af[mi], bf[ji], acc[mi][ji], 0, 0, 0);
  };

  STAGE(0, 0);
  STAGE(1, 1);
  int cb = 0;
  for (int kt = 0; kt < 31; ++kt) {
    asm volatile("s_waitcnt vmcnt(4) lgkmcnt(0)\n\ts_barrier" ::: "memory");
    if (kt < 30) {
      int nb = cb + 2; if (nb >= 3) nb -= 3;
      STAGE(nb, kt + 2);
    }
    COMPUTE(cb);
    if (++cb == 3) cb = 0;
  }
  asm volatile("s_waitcnt vmcnt(0) lgkmcnt(0)\n\ts_barrier" ::: "memory");
  COMPUTE(cb);

  __syncthreads();
  const int h0 = (j0 & 1023) >> 6;
  const int t0 = mt * 32;
  if (src < 2) {
    #pragma unroll
    for (int mi = 0; mi < 4; ++mi) {
      const int tt = wm * 16 + mi * 4 + q4;
      #pragma unroll
      for (int ji = 0; ji < 4; ++ji) {
        const int jj = wn * 64 + ji * 16 + r;
        const int dd = jj & 63, hq = jj >> 6;
        const int cs = (((dd >> 3) ^ (tt & 7)) << 3) + (dd & 7);
        #pragma unroll
        for (int rr = 0; rr < 4; ++rr) {
          float v = acc[mi][ji][rr] + bias[j0 + jj];
          SH[((rr * 2 + hq) * 32 + tt) * 64 + cs] =
              (src == 0) ? f2bf(v * 0.125f) : f2bf(v);
        }
      }
    }
    __syncthreads();
    u16* dst = (src == 0) ? qh : kh;
    #pragma unroll
    for (int c = 0; c < 8; ++c) {
      const int cid = c * 256 + tid;
      const int nn = cid >> 9, hq = (cid >> 8) & 1, tt = (cid >> 3) & 31, dc = cid & 7;
      short8 vv = *(const short8*)(SH + ((nn * 2 + hq) * 32 + tt) * 64 +
                                   ((dc ^ (tt & 7)) << 3));
      *(short8*)(dst + (size_t)(nn * 16 + h0 + hq) * 65536 +
                 (size_t)(t0 + tt) * 64 + dc * 8) = vv;
    }
  } else {
    #pragma unroll
    for (int mi = 0; mi < 4; ++mi) {
      const int tt = wm * 16 + mi * 4 + q4;
      const int tc = tt >> 3, toff = tt & 7;
      #pragma unroll
      for (int ji = 0; ji < 4; ++ji) {
        const int jj = wn * 64 + ji * 16 + r;
        const int dd = jj & 63, hq = jj >> 6;
        #pragma unroll
        for (int rr = 0; rr < 4; ++rr) {
          float v = acc[mi][ji][rr] + bias[j0 + jj];
          SH[((rr * 2 + hq) * 64 + dd) * 32 + ((tc ^ (dd & 3)) << 3) + toff] = f2bf(v);
        }
      }
    }
    __syncthreads();
    #pragma unroll
    for (int c = 0; c < 8; ++c) {
      const int cid = c * 256 + tid;
      const int bbv = cid >> 8, dd = (cid >> 2) & 63, tc = cid & 3;
      short8 vv = *(const short8*)(SH + (bbv * 64 + dd) * 32 +
                                   ((tc ^ (dd & 3)) << 3));
      const int bb = (bbv >> 1) * 16 + h0 + (bbv & 1);
      *(short8*)(vt + (size_t)bb * 65536 + (size_t)dd * 1024 + t0 + tc * 8) = vv;
    }
  }
}

// ---------------------------------------------------------------------------
// Kernel 2: attention context, MFMA flash-style. (r13 exact verified body)
// ---------------------------------------------------------------------------
__global__ __launch_bounds__(256) void attn_ctx_mfma(
    const u16* __restrict__ qh, const u16* __restrict__ kh,
    const u16* __restrict__ vt, u16* __restrict__ ctx,
    float* __restrict__ Zbuf)
{
  __shared__ __align__(16) u16 Ks[2][4096];   // 64 rows x 8 chunks x 8 bf16
  __shared__ __align__(16) u16 Vs[2][4096];
  __shared__ __align__(16) u16 Pl[4][1024];   // per-wave P[16][64], swizzled

  const int tid = threadIdx.x;
  const int wv = tid >> 6, lane = tid & 63, r = lane & 15, q4 = lane >> 4;
  const int b  = blockIdx.y;
  const int lw = blockIdx.x * 64 + wv * 16;
  const int n = b >> 4, h = b & 15;

  const u16* qbase = qh + (size_t)b * 65536;
  const char* kc = (const char*)(kh + (size_t)b * 65536);
  const char* vc = (const char*)(vt + (size_t)b * 65536);
  u16* P = Pl[wv];

  const int ls  = lane >> 3;               // row-in-octet 0..7
  const int swzb = ((lane & 7) ^ ls) << 4; // swizzled 16B-chunk byte offset
  const int iw  = wv * 2;
  const size_t klo = (size_t)iw * 1024 + (size_t)ls * 128 + swzb;   // K row = 128 B
  const size_t vlo = (size_t)iw * 16384 + (size_t)ls * 2048 + swzb; // V row = 2048 B

  const int rsw = r & 7;
  const int c0 = (q4 ^ rsw) << 3;          // u16 offset of logical chunk q4
  const int c1 = ((q4 ^ rsw) ^ 4) << 3;    // logical chunk q4+4

  short8 aq0 = *(const short8*)(qbase + (size_t)(lw + r) * 64 + q4 * 8);
  short8 aq1 = *(const short8*)(qbase + (size_t)(lw + r) * 64 + 32 + q4 * 8);

  f32x4 oc[4];
  #pragma unroll
  for (int ji = 0; ji < 4; ++ji) oc[ji] = (f32x4){0.f, 0.f, 0.f, 0.f};
  float z[4] = {0.f, 0.f, 0.f, 0.f};

  {
    const char* kp = kc + klo;
    const char* vp = vc + vlo;
    u16* kd = &Ks[0][iw * 512];
    u16* vd = &Vs[0][iw * 512];
    __builtin_amdgcn_global_load_lds(kp,          kd,       16, 0, 0);
    __builtin_amdgcn_global_load_lds(kp + 1024,   kd + 512, 16, 0, 0);
    __builtin_amdgcn_global_load_lds(vp,          vd,       16, 0, 0);
    __builtin_amdgcn_global_load_lds(vp + 16384,  vd + 512, 16, 0, 0);
  }

  for (int it = 0; it < 16; ++it) {
    const int cur = it & 1;
    __syncthreads();   // drains vmcnt -> Ks/Vs[cur] staged; prev-iter reads done
    const u16* Kb = Ks[cur];
    const u16* Vb = Vs[cur];

    f32x4 sc[4];
    #pragma unroll
    for (int ji = 0; ji < 4; ++ji) {
      const int row = (ji * 16 + r) * 64;
      short8 bk0 = *(const short8*)(Kb + row + c0);
      short8 bk1 = *(const short8*)(Kb + row + c1);
      f32x4 t = (f32x4){0.f, 0.f, 0.f, 0.f};
      t = __builtin_amdgcn_mfma_f32_16x16x32_bf16(aq0, bk0, t, 0, 0, 0);
      t = __builtin_amdgcn_mfma_f32_16x16x32_bf16(aq1, bk1, t, 0, 0, 0);
      sc[ji] = t;
    }

    if (it < 15) {
      const char* kp = kc + (size_t)(it + 1) * 8192 + klo;  // 64 rows * 128 B
      const char* vp = vc + (size_t)(it + 1) * 128  + vlo;  // 64 cols * 2 B
      u16* kd = &Ks[cur ^ 1][iw * 512];
      u16* vd = &Vs[cur ^ 1][iw * 512];
      __builtin_amdgcn_global_load_lds(kp,          kd,       16, 0, 0);
      __builtin_amdgcn_global_load_lds(kp + 1024,   kd + 512, 16, 0, 0);
      __builtin_amdgcn_global_load_lds(vp,          vd,       16, 0, 0);
      __builtin_amdgcn_global_load_lds(vp + 16384,  vd + 512, 16, 0, 0);
    }

    #pragma unroll
    for (int ji = 0; ji < 4; ++ji) {
      const int cw = ji * 2 + (r >> 3);   // logical 8-elt chunk of col ji*16+r
      #pragma unroll
      for (int rr = 0; rr < 4; ++rr) {
        float e = __expf(sc[ji][rr]);
        z[rr] += e;
        const int row = q4 * 4 + rr;
        P[row * 64 + ((cw ^ (row & 7)) << 3) + (r & 7)] = f2bf(e);
      }
    }
    asm volatile("s_waitcnt lgkmcnt(0)" ::: "memory");
    short8 ap0 = *(const short8*)(P + r * 64 + c0);
    short8 ap1 = *(const short8*)(P + r * 64 + c1);
    #pragma unroll
    for (int ji = 0; ji < 4; ++ji) {
      const int row = (ji * 16 + r) * 64;
      short8 bv0 = *(const short8*)(Vb + row + c0);
      short8 bv1 = *(const short8*)(Vb + row + c1);
      oc[ji] = __builtin_amdgcn_mfma_f32_16x16x32_bf16(ap0, bv0, oc[ji], 0, 0, 0);
      oc[ji] = __builtin_amdgcn_mfma_f32_16x16x32_bf16(ap1, bv1, oc[ji], 0, 0, 0);
    }
  }

  #pragma unroll
  for (int rr = 0; rr < 4; ++rr) {
    float zz = z[rr];
    zz += __shfl_xor(zz, 1);
    zz += __shfl_xor(zz, 2);
    zz += __shfl_xor(zz, 4);
    zz += __shfl_xor(zz, 8);
    z[rr] = zz;
  }

  #pragma unroll
  for (int rr = 0; rr < 4; ++rr) {
    float inv = 1.0f / z[rr];
    int l = lw + q4 * 4 + rr;
    u16* crow = ctx + ((size_t)l * 4 + n) * 1024 + h * 64;
    #pragma unroll
    for (int ji = 0; ji < 4; ++ji)
      crow[ji * 16 + r] = f2bf(oc[ji][rr] * inv);
    if (r == 0) Zbuf[(size_t)b * 1024 + l] = z[rr];
  }
}

// ---------------------------------------------------------------------------
// Kernel 3: fused tail -- out_gemm (blocks 0..511) + attn_w (blocks 512..1535).
// Independent work items; fusing removes one launch and overlaps execution.
// 36 KB LDS overlay (out_gemm: 3-buf A/B; attn_w: Kw 16KB + invZ 4KB).
// ---------------------------------------------------------------------------
__global__ __launch_bounds__(256) void tail_fused(
    const u16* __restrict__ qh, const u16* __restrict__ kh,
    const float* __restrict__ Zbuf, float* __restrict__ out_w,
    const u16* __restrict__ ctx, const u16* __restrict__ W,
    const float* __restrict__ bias, float* __restrict__ out)
{
  __shared__ __align__(16) u16 SH[18432];   // 36 KB

  const int tid = threadIdx.x;
  const int wv = tid >> 6, lane = tid & 63, r = lane & 15, q4 = lane >> 4;

  if (blockIdx.x < 512) {
    // ---------------- out_gemm body (r13, verified) ----------------
    const int wave = wv;
    const int wm   = wave >> 1;
    const int wn   = wave & 1;
    const int orig = blockIdx.x;
    const int nid  = (orig & 7) * 64 + (orig >> 3);
    const int mt   = nid >> 4;
    const int jt   = nid & 15;
    const int m0 = mt * 128;
    const int j0 = jt * 64;

    const int lrow = lane >> 2;
    const int lchk = ((lane & 3) ^ ((lane >> 3) & 3)) << 4;
    const char* Ac = (const char*)ctx;
    const char* Wc = (const char*)W;
    const int fchk = (q4 ^ ((r >> 1) & 3)) << 3;

    f32x4 acc[4][2];
    #pragma unroll
    for (int a = 0; a < 4; ++a)
      #pragma unroll
      for (int b = 0; b < 2; ++b)
        acc[a][b] = (f32x4){0.f, 0.f, 0.f, 0.f};

    auto STAGE = [&](int buf, int kt) {   // 3 gload_lds per wave
      const int kbyte = kt * 64;
      u16* Ad = SH + buf * 4096;
      u16* Bd = SH + 12288 + buf * 2048;
      #pragma unroll
      for (int i = 0; i < 2; ++i) {
        const int g = wave * 2 + i;
        __builtin_amdgcn_global_load_lds(
            (const u16*)(Ac + (size_t)(m0 + g * 16 + lrow) * 2048 + kbyte + lchk),
            Ad + g * 512, 16, 0, 0);
      }
      __builtin_amdgcn_global_load_lds(
          (const u16*)(Wc + (size_t)(j0 + wave * 16 + lrow) * 2048 + kbyte + lchk),
          Bd + wave * 512, 16, 0, 0);
    };

    auto COMPUTE = [&](int cb) {
      const u16* As = SH + cb * 4096;
      const u16* Bs = SH + 12288 + cb * 2048;
      short8 af[4], bf[2];
      #pragma unroll
      for (int mi = 0; mi < 4; ++mi)
        af[mi] = *(const short8*)(&As[(wm * 64 + mi * 16 + r) * 32 + fchk]);
      #pragma unroll
      for (int ji = 0; ji < 2; ++ji)
        bf[ji] = *(const short8*)(&Bs[(wn * 32 + ji * 16 + r) * 32 + fchk]);
      #pragma unroll
      for (int mi = 0; mi < 4; ++mi)
        #pragma unroll
        for (int ji = 0; ji < 2; ++ji)
          acc[mi][ji] = __builtin_amdgcn_mfma_f32_16x16x32_bf16(af[mi], bf[ji], acc[mi][ji], 0, 0, 0);
    };

    STAGE(0, 0);
    STAGE(1, 1);
    int cb = 0;
    for (int kt = 0; kt < 31; ++kt) {
      asm volatile("s_waitcnt vmcnt(3) lgkmcnt(0)\n\ts_barrier" ::: "memory");
      if (kt < 30) {
        int nb = cb + 2; if (nb >= 3) nb -= 3;
        STAGE(nb, kt + 2);
      }
      COMPUTE(cb);
      if (++cb == 3) cb = 0;
    }
    asm volatile("s_waitcnt vmcnt(0) lgkmcnt(0)\n\ts_barrier" ::: "memory");
    COMPUTE(cb);

    #pragma unroll
    for (int mi = 0; mi < 4; ++mi) {
      #pragma unroll
      for (int ji = 0; ji < 2; ++ji) {
        #pragma unroll
        for (int rr = 0; rr < 4; ++rr) {
          int m = m0 + wm * 64 + mi * 16 + q4 * 4 + rr;
          int j = j0 + wn * 32 + ji * 16 + r;
          out[(size_t)m * 1024 + j] = acc[mi][ji][rr] + bias[j];
        }
      }
    }
  } else {
    // ---------------- attn_w body (r7, verified) ----------------
    const int id2 = blockIdx.x - 512;
    const int lt = id2 & 15;
    const int st = (id2 >> 4) & 15;
    const int n  = id2 >> 8;
    const int l0 = lt * 64;
    const int s0 = st * 64;
    const int lw = l0 + wv * 16;

    u16* Kw = SH;                              // 2 x 4096 u16 = 16 KB
    float* invZ = (float*)(SH + 8192);         // 16*64 floats = 4 KB

    const char* khc = (const char*)kh + (size_t)n * 2097152;

    const int ls  = lane >> 3;
    const int swzb = ((lane & 7) ^ ls) << 4;
    const int iw  = wv * 2;
    const size_t klo = (size_t)s0 * 128 + (size_t)iw * 1024 + (size_t)ls * 128 + swzb;

    const int rsw = r & 7;
    const int c0 = (q4 ^ rsw) << 3;
    const int c1 = ((q4 ^ rsw) ^ 4) << 3;

    for (int i = tid; i < 1024; i += 256) {
      int hh = i >> 6, row = i & 63;
      invZ[hh * 64 + row] = 1.0f / (Zbuf[(size_t)(n * 16 + hh) * 1024 + l0 + row] * 16.0f);
    }

    {
      const char* kp = khc + klo;
      u16* kd = &Kw[iw * 512];
      __builtin_amdgcn_global_load_lds(kp,        kd,       16, 0, 0);
      __builtin_amdgcn_global_load_lds(kp + 1024, kd + 512, 16, 0, 0);
    }
    const u16* q0 = qh + (size_t)(n * 16) * 65536;
    short8 aqc0 = *(const short8*)(q0 + (size_t)(lw + r) * 64 + q4 * 8);
    short8 aqc1 = *(const short8*)(q0 + (size_t)(lw + r) * 64 + 32 + q4 * 8);

    f32x4 wacc[4];
    #pragma unroll
    for (int ji = 0; ji < 4; ++ji) wacc[ji] = (f32x4){0.f, 0.f, 0.f, 0.f};

    for (int hh = 0; hh < 16; ++hh) {
      const int cur = hh & 1;
      __syncthreads();   // Kw[cur] staged (and invZ on first iter)
      if (hh < 15) {
        const char* kp = khc + (size_t)(hh + 1) * 131072 + klo;
        u16* kd = &Kw[(cur ^ 1) * 4096 + iw * 512];
        __builtin_amdgcn_global_load_lds(kp,        kd,       16, 0, 0);
        __builtin_amdgcn_global_load_lds(kp + 1024, kd + 512, 16, 0, 0);
      }
      const int hn = (hh < 15) ? hh + 1 : hh;
      const u16* qn = qh + (size_t)(n * 16 + hn) * 65536;
      short8 an0 = *(const short8*)(qn + (size_t)(lw + r) * 64 + q4 * 8);
      short8 an1 = *(const short8*)(qn + (size_t)(lw + r) * 64 + 32 + q4 * 8);

      const u16* Kb = Kw + cur * 4096;
      f32x4 sc[4];
      #pragma unroll
      for (int ji = 0; ji < 4; ++ji) {
        const int row = (ji * 16 + r) * 64;
        short8 bk0 = *(const short8*)(Kb + row + c0);
        short8 bk1 = *(const short8*)(Kb + row + c1);
        f32x4 t = (f32x4){0.f, 0.f, 0.f, 0.f};
        t = __builtin_amdgcn_mfma_f32_16x16x32_bf16(aqc0, bk0, t, 0, 0, 0);
        t = __builtin_amdgcn_mfma_f32_16x16x32_bf16(aqc1, bk1, t, 0, 0, 0);
        sc[ji] = t;
      }
      #pragma unroll
      for (int rr = 0; rr < 4; ++rr) {
        float iv = invZ[hh * 64 + wv * 16 + q4 * 4 + rr];
        #pragma unroll
        for (int ji = 0; ji < 4; ++ji)
          wacc[ji][rr] += __expf(sc[ji][rr]) * iv;
      }
      aqc0 = an0; aqc1 = an1;
    }

    #pragma unroll
    for (int ji = 0; ji < 4; ++ji)
      #pragma unroll
      for (int rr = 0; rr < 4; ++rr) {
        int row = lw + q4 * 4 + rr;
        int col = s0 + ji * 16 + r;
        out_w[(size_t)n * 1048576 + (size_t)row * 1024 + col] = wacc[ji][rr];
      }
  }
}

// ---------------------------------------------------------------------------
extern "C" void kernel_launch(void* const* d_in, const int* in_sizes, int n_in,
                              void* d_out, int out_size, void* d_ws, size_t ws_size,
                              hipStream_t stream) {
  const float* query = (const float*)d_in[0];
  const float* key   = (const float*)d_in[1];
  const float* value = (const float*)d_in[2];
  const float* W_in  = (const float*)d_in[3];
  const float* b_in  = (const float*)d_in[4];
  const float* W_out = (const float*)d_in[5];
  const float* b_out = (const float*)d_in[6];
  float* out = (float*)d_out;

  // ws (~64.3 MB): qb 8 | kb 8 | vb 8 | Wib 6 | Wob 2 | qh 8 | kh 8 | vt 8 | ctx 8 | Z .25
  u16* qb  = (u16*)d_ws;
  u16* kb  = qb  + (size_t)4194304;
  u16* vb  = kb  + (size_t)4194304;
  u16* Wib = vb  + (size_t)4194304;
  u16* Wob = Wib + (size_t)3145728;
  u16* qh  = Wob + (size_t)1048576;
  u16* kh  = qh  + (size_t)4194304;
  u16* vt  = kh  + (size_t)4194304;
  u16* ctx = vt  + (size_t)4194304;
  float* Zbuf = (float*)(ctx + (size_t)4194304);

  convert_bf16<<<dim3(512, 5), 256, 0, stream>>>(query, key, value, W_in, W_out,
                                                 qb, kb, vb, Wib, Wob);
  qkv_gemm<<<dim3(24, 32), 256, 0, stream>>>(qb, kb, vb, Wib, b_in, qh, kh, vt);
  attn_ctx_mfma<<<dim3(16, 64), 256, 0, stream>>>(qh, kh, vt, ctx, Zbuf);
  tail_fused<<<dim3(1536), 256, 0, stream>>>(qh, kh, Zbuf, out + (size_t)4194304,
                                             ctx, Wob, b_out, out);
}

// Round 10
// 223.303 us; speedup vs baseline: 1.1007x; 1.0057x over previous
//
#include <hip/hip_runtime.h>

// MHA forward. L=S=1024, N=4, E=1024, H=16, hd=64, B=N*H=64, M=L*N=4096
// Inputs fp32, outputs fp32 (out0=attn_output 4.19M, out1=attn_weights 4.19M @+4194304).
// Round 16: attn_w phase (dominant part of tail_fused) still had the r9
// anti-pattern: per-head K staged 1-deep + full __syncthreads drain (16x).
// Rewritten to the qkv-proven 3-buffer counted-vmcnt recipe: stage head hh+2,
// steady `s_waitcnt vmcnt(4) lgkmcnt(0); s_barrier` (4 = 2 in-flight K-stage
// loads of hh+1 + 2 Q-prefetch dwordx4 issued first in the body), peeled final
// head vmcnt(0). Kw 3x8KB + invZ 4KB = 28KB <= 36KB envelope (occupancy
// unchanged). Same loads/math/order -> bit-identical numerics.
// convert/qkv/attn_ctx/out_gemm unchanged from r15 (verified).
typedef unsigned short u16;
typedef __attribute__((ext_vector_type(8))) short short8;   // 8 bf16 (4 VGPRs)
typedef __attribute__((ext_vector_type(4))) float f32x4;    // MFMA accumulator

__device__ __forceinline__ u16 f2bf(float f) {  // RNE
  unsigned int i = __float_as_uint(f);
  i += 0x7fffu + ((i >> 16) & 1u);
  return (u16)(i >> 16);
}

__device__ __forceinline__ short8 cvt8(const float* p) {
  float4 a = ((const float4*)p)[0];
  float4 b = ((const float4*)p)[1];
  short8 r;
  r[0] = (short)f2bf(a.x); r[1] = (short)f2bf(a.y);
  r[2] = (short)f2bf(a.z); r[3] = (short)f2bf(a.w);
  r[4] = (short)f2bf(b.x); r[5] = (short)f2bf(b.y);
  r[6] = (short)f2bf(b.z); r[7] = (short)f2bf(b.w);
  return r;
}

// ---------------------------------------------------------------------------
// Kernel 0: one-shot fp32 -> bf16 conversion of q/k/v/W_in/W_out. (unchanged)
// ---------------------------------------------------------------------------
__global__ __launch_bounds__(256) void convert_bf16(
    const float* __restrict__ q, const float* __restrict__ k,
    const float* __restrict__ v, const float* __restrict__ Wi,
    const float* __restrict__ Wo,
    u16* __restrict__ qb, u16* __restrict__ kb, u16* __restrict__ vb,
    u16* __restrict__ Wib, u16* __restrict__ Wob)
{
  const float* src; u16* dst; int len8;
  switch (blockIdx.y) {
    case 0:  src = q;  dst = qb;  len8 = 524288; break;  // 4M elts
    case 1:  src = k;  dst = kb;  len8 = 524288; break;
    case 2:  src = v;  dst = vb;  len8 = 524288; break;
    case 3:  src = Wi; dst = Wib; len8 = 393216; break;  // 3M elts
    default: src = Wo; dst = Wob; len8 = 131072; break;  // 1M elts
  }
  int stride = gridDim.x * 256;
  for (int i = blockIdx.x * 256 + threadIdx.x; i < len8; i += stride)
    *(short8*)(dst + (size_t)i * 8) = cvt8(src + (size_t)i * 8);
}

// ---------------------------------------------------------------------------
// Kernel 1: packed QKV projection. (unchanged from r13 -- verified)
// 128x128 tile, BK=32, 3-buffer counted-vmcnt pipeline, coalesced epilogue.
// ---------------------------------------------------------------------------
__global__ __launch_bounds__(256) void qkv_gemm(
    const u16* __restrict__ qb, const u16* __restrict__ kb,
    const u16* __restrict__ vb, const u16* __restrict__ W,
    const float* __restrict__ bias,
    u16* __restrict__ qh, u16* __restrict__ kh, u16* __restrict__ vt)
{
  __shared__ __align__(16) u16 SH[24576];

  const int tid  = threadIdx.x;
  const int wave = tid >> 6;
  const int lane = tid & 63;
  const int r    = lane & 15;
  const int q4   = lane >> 4;
  const int wm   = wave >> 1;
  const int wn   = wave & 1;

  const int orig = blockIdx.y * 24 + blockIdx.x;
  const int nid  = (orig & 7) * 96 + (orig >> 3);
  const int mt   = nid / 24;
  const int jt   = nid - mt * 24;
  const int src  = jt >> 3;
  const u16* X = (src == 0) ? qb : (src == 1) ? kb : vb;
  const int m0 = mt * 128;
  const int j0 = jt * 128;

  const int lrow = lane >> 2;
  const int lchk = ((lane & 3) ^ ((lane >> 3) & 3)) << 4;
  const char* Xc = (const char*)X;
  const char* Wc = (const char*)W;
  const int fchk = (q4 ^ ((r >> 1) & 3)) << 3;

  f32x4 acc[4][4];
  #pragma unroll
  for (int a = 0; a < 4; ++a)
    #pragma unroll
    for (int b = 0; b < 4; ++b)
      acc[a][b] = (f32x4){0.f, 0.f, 0.f, 0.f};

  auto STAGE = [&](int buf, int kt) {   // 4 gload_lds per wave
    const int kbyte = kt * 64;
    u16* Ad = SH + buf * 4096;
    u16* Bd = SH + 12288 + buf * 4096;
    #pragma unroll
    for (int i = 0; i < 2; ++i) {
      const int g = wave * 2 + i;
      __builtin_amdgcn_global_load_lds(
          (const u16*)(Xc + (size_t)(m0 + g * 16 + lrow) * 2048 + kbyte + lchk),
          Ad + g * 512, 16, 0, 0);
      __builtin_amdgcn_global_load_lds(
          (const u16*)(Wc + (size_t)(j0 + g * 16 + lrow) * 2048 + kbyte + lchk),
          Bd + g * 512, 16, 0, 0);
    }
  };

  auto COMPUTE = [&](int cb) {
    const u16* As = SH + cb * 4096;
    const u16* Bs = SH + 12288 + cb * 4096;
    short8 af[4], bf[4];
    #pragma unroll
    for (int mi = 0; mi < 4; ++mi)
      af[mi] = *(const short8*)(&As[(wm * 64 + mi * 16 + r) * 32 + fchk]);
    #pragma unroll
    for (int ji = 0; ji < 4; ++ji)
      bf[ji] = *(const short8*)(&Bs[(wn * 64 + ji * 16 + r) * 32 + fchk]);
    #pragma unroll
    for (int mi = 0; mi < 4; ++mi)
      #pragma unroll
      for (int ji = 0; ji < 4; ++ji)
        acc[mi][ji] = __builtin_amdgcn_mfma_f32_16x16x32_bf16(af[mi], bf[ji], acc[mi][ji], 0, 0, 0);
  };

  STAGE(0, 0);
  STAGE(1, 1);
  int cb = 0;
  for (int kt = 0; kt < 31; ++kt) {
    asm volatile("s_waitcnt vmcnt(4) lgkmcnt(0)\n\ts_barrier" ::: "memory");
    if (kt < 30) {
      int nb = cb + 2; if (nb >= 3) nb -= 3;
      STAGE(nb, kt + 2);
    }
    COMPUTE(cb);
    if (++cb == 3) cb = 0;
  }
  asm volatile("s_waitcnt vmcnt(0) lgkmcnt(0)\n\ts_barrier" ::: "memory");
  COMPUTE(cb);

  __syncthreads();
  const int h0 = (j0 & 1023) >> 6;
  const int t0 = mt * 32;
  if (src < 2) {
    #pragma unroll
    for (int mi = 0; mi < 4; ++mi) {
      const int tt = wm * 16 + mi * 4 + q4;
      #pragma unroll
      for (int ji = 0; ji < 4; ++ji) {
        const int jj = wn * 64 + ji * 16 + r;
        const int dd = jj & 63, hq = jj >> 6;
        const int cs = (((dd >> 3) ^ (tt & 7)) << 3) + (dd & 7);
        #pragma unroll
        for (int rr = 0; rr < 4; ++rr) {
          float v = acc[mi][ji][rr] + bias[j0 + jj];
          SH[((rr * 2 + hq) * 32 + tt) * 64 + cs] =
              (src == 0) ? f2bf(v * 0.125f) : f2bf(v);
        }
      }
    }
    __syncthreads();
    u16* dst = (src == 0) ? qh : kh;
    #pragma unroll
    for (int c = 0; c < 8; ++c) {
      const int cid = c * 256 + tid;
      const int nn = cid >> 9, hq = (cid >> 8) & 1, tt = (cid >> 3) & 31, dc = cid & 7;
      short8 vv = *(const short8*)(SH + ((nn * 2 + hq) * 32 + tt) * 64 +
                                   ((dc ^ (tt & 7)) << 3));
      *(short8*)(dst + (size_t)(nn * 16 + h0 + hq) * 65536 +
                 (size_t)(t0 + tt) * 64 + dc * 8) = vv;
    }
  } else {
    #pragma unroll
    for (int mi = 0; mi < 4; ++mi) {
      const int tt = wm * 16 + mi * 4 + q4;
      const int tc = tt >> 3, toff = tt & 7;
      #pragma unroll
      for (int ji = 0; ji < 4; ++ji) {
        const int jj = wn * 64 + ji * 16 + r;
        const int dd = jj & 63, hq = jj >> 6;
        #pragma unroll
        for (int rr = 0; rr < 4; ++rr) {
          float v = acc[mi][ji][rr] + bias[j0 + jj];
          SH[((rr * 2 + hq) * 64 + dd) * 32 + ((tc ^ (dd & 3)) << 3) + toff] = f2bf(v);
        }
      }
    }
    __syncthreads();
    #pragma unroll
    for (int c = 0; c < 8; ++c) {
      const int cid = c * 256 + tid;
      const int bbv = cid >> 8, dd = (cid >> 2) & 63, tc = cid & 3;
      short8 vv = *(const short8*)(SH + (bbv * 64 + dd) * 32 +
                                   ((tc ^ (dd & 3)) << 3));
      const int bb = (bbv >> 1) * 16 + h0 + (bbv & 1);
      *(short8*)(vt + (size_t)bb * 65536 + (size_t)dd * 1024 + t0 + tc * 8) = vv;
    }
  }
}

// ---------------------------------------------------------------------------
// Kernel 2: attention context, MFMA flash-style. (r13 exact verified body)
// ---------------------------------------------------------------------------
__global__ __launch_bounds__(256) void attn_ctx_mfma(
    const u16* __restrict__ qh, const u16* __restrict__ kh,
    const u16* __restrict__ vt, u16* __restrict__ ctx,
    float* __restrict__ Zbuf)
{
  __shared__ __align__(16) u16 Ks[2][4096];   // 64 rows x 8 chunks x 8 bf16
  __shared__ __align__(16) u16 Vs[2][4096];
  __shared__ __align__(16) u16 Pl[4][1024];   // per-wave P[16][64], swizzled

  const int tid = threadIdx.x;
  const int wv = tid >> 6, lane = tid & 63, r = lane & 15, q4 = lane >> 4;
  const int b  = blockIdx.y;
  const int lw = blockIdx.x * 64 + wv * 16;
  const int n = b >> 4, h = b & 15;

  const u16* qbase = qh + (size_t)b * 65536;
  const char* kc = (const char*)(kh + (size_t)b * 65536);
  const char* vc = (const char*)(vt + (size_t)b * 65536);
  u16* P = Pl[wv];

  const int ls  = lane >> 3;               // row-in-octet 0..7
  const int swzb = ((lane & 7) ^ ls) << 4; // swizzled 16B-chunk byte offset
  const int iw  = wv * 2;
  const size_t klo = (size_t)iw * 1024 + (size_t)ls * 128 + swzb;   // K row = 128 B
  const size_t vlo = (size_t)iw * 16384 + (size_t)ls * 2048 + swzb; // V row = 2048 B

  const int rsw = r & 7;
  const int c0 = (q4 ^ rsw) << 3;          // u16 offset of logical chunk q4
  const int c1 = ((q4 ^ rsw) ^ 4) << 3;    // logical chunk q4+4

  short8 aq0 = *(const short8*)(qbase + (size_t)(lw + r) * 64 + q4 * 8);
  short8 aq1 = *(const short8*)(qbase + (size_t)(lw + r) * 64 + 32 + q4 * 8);

  f32x4 oc[4];
  #pragma unroll
  for (int ji = 0; ji < 4; ++ji) oc[ji] = (f32x4){0.f, 0.f, 0.f, 0.f};
  float z[4] = {0.f, 0.f, 0.f, 0.f};

  {
    const char* kp = kc + klo;
    const char* vp = vc + vlo;
    u16* kd = &Ks[0][iw * 512];
    u16* vd = &Vs[0][iw * 512];
    __builtin_amdgcn_global_load_lds(kp,          kd,       16, 0, 0);
    __builtin_amdgcn_global_load_lds(kp + 1024,   kd + 512, 16, 0, 0);
    __builtin_amdgcn_global_load_lds(vp,          vd,       16, 0, 0);
    __builtin_amdgcn_global_load_lds(vp + 16384,  vd + 512, 16, 0, 0);
  }

  for (int it = 0; it < 16; ++it) {
    const int cur = it & 1;
    __syncthreads();   // drains vmcnt -> Ks/Vs[cur] staged; prev-iter reads done
    const u16* Kb = Ks[cur];
    const u16* Vb = Vs[cur];

    f32x4 sc[4];
    #pragma unroll
    for (int ji = 0; ji < 4; ++ji) {
      const int row = (ji * 16 + r) * 64;
      short8 bk0 = *(const short8*)(Kb + row + c0);
      short8 bk1 = *(const short8*)(Kb + row + c1);
      f32x4 t = (f32x4){0.f, 0.f, 0.f, 0.f};
      t = __builtin_amdgcn_mfma_f32_16x16x32_bf16(aq0, bk0, t, 0, 0, 0);
      t = __builtin_amdgcn_mfma_f32_16x16x32_bf16(aq1, bk1, t, 0, 0, 0);
      sc[ji] = t;
    }

    if (it < 15) {
      const char* kp = kc + (size_t)(it + 1) * 8192 + klo;  // 64 rows * 128 B
      const char* vp = vc + (size_t)(it + 1) * 128  + vlo;  // 64 cols * 2 B
      u16* kd = &Ks[cur ^ 1][iw * 512];
      u16* vd = &Vs[cur ^ 1][iw * 512];
      __builtin_amdgcn_global_load_lds(kp,          kd,       16, 0, 0);
      __builtin_amdgcn_global_load_lds(kp + 1024,   kd + 512, 16, 0, 0);
      __builtin_amdgcn_global_load_lds(vp,          vd,       16, 0, 0);
      __builtin_amdgcn_global_load_lds(vp + 16384,  vd + 512, 16, 0, 0);
    }

    #pragma unroll
    for (int ji = 0; ji < 4; ++ji) {
      const int cw = ji * 2 + (r >> 3);   // logical 8-elt chunk of col ji*16+r
      #pragma unroll
      for (int rr = 0; rr < 4; ++rr) {
        float e = __expf(sc[ji][rr]);
        z[rr] += e;
        const int row = q4 * 4 + rr;
        P[row * 64 + ((cw ^ (row & 7)) << 3) + (r & 7)] = f2bf(e);
      }
    }
    asm volatile("s_waitcnt lgkmcnt(0)" ::: "memory");
    short8 ap0 = *(const short8*)(P + r * 64 + c0);
    short8 ap1 = *(const short8*)(P + r * 64 + c1);
    #pragma unroll
    for (int ji = 0; ji < 4; ++ji) {
      const int row = (ji * 16 + r) * 64;
      short8 bv0 = *(const short8*)(Vb + row + c0);
      short8 bv1 = *(const short8*)(Vb + row + c1);
      oc[ji] = __builtin_amdgcn_mfma_f32_16x16x32_bf16(ap0, bv0, oc[ji], 0, 0, 0);
      oc[ji] = __builtin_amdgcn_mfma_f32_16x16x32_bf16(ap1, bv1, oc[ji], 0, 0, 0);
    }
  }

  #pragma unroll
  for (int rr = 0; rr < 4; ++rr) {
    float zz = z[rr];
    zz += __shfl_xor(zz, 1);
    zz += __shfl_xor(zz, 2);
    zz += __shfl_xor(zz, 4);
    zz += __shfl_xor(zz, 8);
    z[rr] = zz;
  }

  #pragma unroll
  for (int rr = 0; rr < 4; ++rr) {
    float inv = 1.0f / z[rr];
    int l = lw + q4 * 4 + rr;
    u16* crow = ctx + ((size_t)l * 4 + n) * 1024 + h * 64;
    #pragma unroll
    for (int ji = 0; ji < 4; ++ji)
      crow[ji * 16 + r] = f2bf(oc[ji][rr] * inv);
    if (r == 0) Zbuf[(size_t)b * 1024 + l] = z[rr];
  }
}

// ---------------------------------------------------------------------------
// Kernel 3: fused tail -- out_gemm (blocks 0..511) + attn_w (blocks 512..1535).
// Round-16: attn_w head-loop now 3-buffer counted-vmcnt (stage hh+2,
// steady vmcnt(4)+lgkmcnt(0)+s_barrier, peeled final head vmcnt(0)).
// LDS overlay 36 KB (out_gemm: 3-buf A/B; attn_w: Kw 24KB + invZ 4KB).
// ---------------------------------------------------------------------------
__global__ __launch_bounds__(256) void tail_fused(
    const u16* __restrict__ qh, const u16* __restrict__ kh,
    const float* __restrict__ Zbuf, float* __restrict__ out_w,
    const u16* __restrict__ ctx, const u16* __restrict__ W,
    const float* __restrict__ bias, float* __restrict__ out)
{
  __shared__ __align__(16) u16 SH[18432];   // 36 KB

  const int tid = threadIdx.x;
  const int wv = tid >> 6, lane = tid & 63, r = lane & 15, q4 = lane >> 4;

  if (blockIdx.x < 512) {
    // ---------------- out_gemm body (r13, verified) ----------------
    const int wave = wv;
    const int wm   = wave >> 1;
    const int wn   = wave & 1;
    const int orig = blockIdx.x;
    const int nid  = (orig & 7) * 64 + (orig >> 3);
    const int mt   = nid >> 4;
    const int jt   = nid & 15;
    const int m0 = mt * 128;
    const int j0 = jt * 64;

    const int lrow = lane >> 2;
    const int lchk = ((lane & 3) ^ ((lane >> 3) & 3)) << 4;
    const char* Ac = (const char*)ctx;
    const char* Wc = (const char*)W;
    const int fchk = (q4 ^ ((r >> 1) & 3)) << 3;

    f32x4 acc[4][2];
    #pragma unroll
    for (int a = 0; a < 4; ++a)
      #pragma unroll
      for (int b = 0; b < 2; ++b)
        acc[a][b] = (f32x4){0.f, 0.f, 0.f, 0.f};

    auto STAGE = [&](int buf, int kt) {   // 3 gload_lds per wave
      const int kbyte = kt * 64;
      u16* Ad = SH + buf * 4096;
      u16* Bd = SH + 12288 + buf * 2048;
      #pragma unroll
      for (int i = 0; i < 2; ++i) {
        const int g = wave * 2 + i;
        __builtin_amdgcn_global_load_lds(
            (const u16*)(Ac + (size_t)(m0 + g * 16 + lrow) * 2048 + kbyte + lchk),
            Ad + g * 512, 16, 0, 0);
      }
      __builtin_amdgcn_global_load_lds(
          (const u16*)(Wc + (size_t)(j0 + wave * 16 + lrow) * 2048 + kbyte + lchk),
          Bd + wave * 512, 16, 0, 0);
    };

    auto COMPUTE = [&](int cb) {
      const u16* As = SH + cb * 4096;
      const u16* Bs = SH + 12288 + cb * 2048;
      short8 af[4], bf[2];
      #pragma unroll
      for (int mi = 0; mi < 4; ++mi)
        af[mi] = *(const short8*)(&As[(wm * 64 + mi * 16 + r) * 32 + fchk]);
      #pragma unroll
      for (int ji = 0; ji < 2; ++ji)
        bf[ji] = *(const short8*)(&Bs[(wn * 32 + ji * 16 + r) * 32 + fchk]);
      #pragma unroll
      for (int mi = 0; mi < 4; ++mi)
        #pragma unroll
        for (int ji = 0; ji < 2; ++ji)
          acc[mi][ji] = __builtin_amdgcn_mfma_f32_16x16x32_bf16(af[mi], bf[ji], acc[mi][ji], 0, 0, 0);
    };

    STAGE(0, 0);
    STAGE(1, 1);
    int cb = 0;
    for (int kt = 0; kt < 31; ++kt) {
      asm volatile("s_waitcnt vmcnt(3) lgkmcnt(0)\n\ts_barrier" ::: "memory");
      if (kt < 30) {
        int nb = cb + 2; if (nb >= 3) nb -= 3;
        STAGE(nb, kt + 2);
      }
      COMPUTE(cb);
      if (++cb == 3) cb = 0;
    }
    asm volatile("s_waitcnt vmcnt(0) lgkmcnt(0)\n\ts_barrier" ::: "memory");
    COMPUTE(cb);

    #pragma unroll
    for (int mi = 0; mi < 4; ++mi) {
      #pragma unroll
      for (int ji = 0; ji < 2; ++ji) {
        #pragma unroll
        for (int rr = 0; rr < 4; ++rr) {
          int m = m0 + wm * 64 + mi * 16 + q4 * 4 + rr;
          int j = j0 + wn * 32 + ji * 16 + r;
          out[(size_t)m * 1024 + j] = acc[mi][ji][rr] + bias[j];
        }
      }
    }
  } else {
    // ---------------- attn_w body: 3-buffer counted-vmcnt head loop --------
    const int id2 = blockIdx.x - 512;
    const int lt = id2 & 15;
    const int st = (id2 >> 4) & 15;
    const int n  = id2 >> 8;
    const int l0 = lt * 64;
    const int s0 = st * 64;
    const int lw = l0 + wv * 16;

    u16* Kw = SH;                              // 3 x 4096 u16 = 24 KB
    float* invZ = (float*)(SH + 12288);        // 16*64 floats = 4 KB

    const char* khc = (const char*)kh + (size_t)n * 2097152;

    const int ls  = lane >> 3;
    const int swzb = ((lane & 7) ^ ls) << 4;
    const int iw  = wv * 2;
    const size_t klo = (size_t)s0 * 128 + (size_t)iw * 1024 + (size_t)ls * 128 + swzb;

    const int rsw = r & 7;
    const int c0 = (q4 ^ rsw) << 3;
    const int c1 = ((q4 ^ rsw) ^ 4) << 3;

    for (int i = tid; i < 1024; i += 256) {
      int hh = i >> 6, row = i & 63;
      invZ[hh * 64 + row] = 1.0f / (Zbuf[(size_t)(n * 16 + hh) * 1024 + l0 + row] * 16.0f);
    }

    auto STAGEK = [&](int buf, int hh) {   // 2 gload_lds per wave
      const char* kp = khc + (size_t)hh * 131072 + klo;
      u16* kd = &Kw[buf * 4096 + iw * 512];
      __builtin_amdgcn_global_load_lds(kp,        kd,       16, 0, 0);
      __builtin_amdgcn_global_load_lds(kp + 1024, kd + 512, 16, 0, 0);
    };

    STAGEK(0, 0);
    STAGEK(1, 1);
    const u16* q0 = qh + (size_t)(n * 16) * 65536;
    short8 aqc0 = *(const short8*)(q0 + (size_t)(lw + r) * 64 + q4 * 8);
    short8 aqc1 = *(const short8*)(q0 + (size_t)(lw + r) * 64 + 32 + q4 * 8);

    f32x4 wacc[4];
    #pragma unroll
    for (int ji = 0; ji < 4; ++ji) wacc[ji] = (f32x4){0.f, 0.f, 0.f, 0.f};

    auto HEAD = [&](int hh, int cbw, short8& an0, short8& an1) {
      // Q-prefetch FIRST (so compiler's pre-QK wait for Q never drains the
      // younger K-stage issued below).
      const int hn = (hh < 15) ? hh + 1 : hh;
      const u16* qn = qh + (size_t)(n * 16 + hn) * 65536;
      an0 = *(const short8*)(qn + (size_t)(lw + r) * 64 + q4 * 8);
      an1 = *(const short8*)(qn + (size_t)(lw + r) * 64 + 32 + q4 * 8);
      if (hh < 14) {
        int nb = cbw + 2; if (nb >= 3) nb -= 3;
        STAGEK(nb, hh + 2);
      }
      const u16* Kb = Kw + cbw * 4096;
      f32x4 sc[4];
      #pragma unroll
      for (int ji = 0; ji < 4; ++ji) {
        const int row = (ji * 16 + r) * 64;
        short8 bk0 = *(const short8*)(Kb + row + c0);
        short8 bk1 = *(const short8*)(Kb + row + c1);
        f32x4 t = (f32x4){0.f, 0.f, 0.f, 0.f};
        t = __builtin_amdgcn_mfma_f32_16x16x32_bf16(aqc0, bk0, t, 0, 0, 0);
        t = __builtin_amdgcn_mfma_f32_16x16x32_bf16(aqc1, bk1, t, 0, 0, 0);
        sc[ji] = t;
      }
      #pragma unroll
      for (int rr = 0; rr < 4; ++rr) {
        float iv = invZ[hh * 64 + wv * 16 + q4 * 4 + rr];
        #pragma unroll
        for (int ji = 0; ji < 4; ++ji)
          wacc[ji][rr] += __expf(sc[ji][rr]) * iv;
      }
      aqc0 = an0; aqc1 = an1;
    };

    int cbw = 0;
    short8 an0, an1;
    for (int hh = 0; hh < 15; ++hh) {
      // vmcnt(4): own STAGEK(hh) drained; leaves STAGEK(hh+1)'s 2 + Q-prefetch
      // 2 in flight. lgkmcnt(0): invZ ds_writes + prev ds_reads complete
      // before the barrier (rule-#18).
      asm volatile("s_waitcnt vmcnt(4) lgkmcnt(0)\n\ts_barrier" ::: "memory");
      HEAD(hh, cbw, an0, an1);
      if (++cbw == 3) cbw = 0;
    }
    // FINAL head: full drain (vmcnt(4) would be a no-op here).
    asm volatile("s_waitcnt vmcnt(0) lgkmcnt(0)\n\ts_barrier" ::: "memory");
    HEAD(15, cbw, an0, an1);

    #pragma unroll
    for (int ji = 0; ji < 4; ++ji)
      #pragma unroll
      for (int rr = 0; rr < 4; ++rr) {
        int row = lw + q4 * 4 + rr;
        int col = s0 + ji * 16 + r;
        out_w[(size_t)n * 1048576 + (size_t)row * 1024 + col] = wacc[ji][rr];
      }
  }
}

// ---------------------------------------------------------------------------
extern "C" void kernel_launch(void* const* d_in, const int* in_sizes, int n_in,
                              void* d_out, int out_size, void* d_ws, size_t ws_size,
                              hipStream_t stream) {
  const float* query = (const float*)d_in[0];
  const float* key   = (const float*)d_in[1];
  const float* value = (const float*)d_in[2];
  const float* W_in  = (const float*)d_in[3];
  const float* b_in  = (const float*)d_in[4];
  const float* W_out = (const float*)d_in[5];
  const float* b_out = (const float*)d_in[6];
  float* out = (float*)d_out;

  // ws (~64.3 MB): qb 8 | kb 8 | vb 8 | Wib 6 | Wob 2 | qh 8 | kh 8 | vt 8 | ctx 8 | Z .25
  u16* qb  = (u16*)d_ws;
  u16* kb  = qb  + (size_t)4194304;
  u16* vb  = kb  + (size_t)4194304;
  u16* Wib = vb  + (size_t)4194304;
  u16* Wob = Wib + (size_t)3145728;
  u16* qh  = Wob + (size_t)1048576;
  u16* kh  = qh  + (size_t)4194304;
  u16* vt  = kh  + (size_t)4194304;
  u16* ctx = vt  + (size_t)4194304;
  float* Zbuf = (float*)(ctx + (size_t)4194304);

  convert_bf16<<<dim3(512, 5), 256, 0, stream>>>(query, key, value, W_in, W_out,
                                                 qb, kb, vb, Wib, Wob);
  qkv_gemm<<<dim3(24, 32), 256, 0, stream>>>(qb, kb, vb, Wib, b_in, qh, kh, vt);
  attn_ctx_mfma<<<dim3(16, 64), 256, 0, stream>>>(qh, kh, vt, ctx, Zbuf);
  tail_fused<<<dim3(1536), 256, 0, stream>>>(qh, kh, Zbuf, out + (size_t)4194304,
                                             ctx, Wob, b_out, out);
}

// Round 11
// 213.932 us; speedup vs baseline: 1.1489x; 1.0438x over previous
//
#include <hip/hip_runtime.h>

// MHA forward. L=S=1024, N=4, E=1024, H=16, hd=64, B=N*H=64, M=L*N=4096
// Inputs fp32, outputs fp32 (out0=attn_output 4.19M, out1=attn_weights 4.19M @+4194304).
// Round 17: r16's counted-vmcnt on attn_w was NULL -> schedule exonerated there.
// This round: attn_ctx blocks widened 256->512 threads (128 Q-rows, grid 8x64).
// Per-wave code identical (16 rows, own P buffer -> bit-identical numerics);
// 8 waves share each staged 16KB K/V tile: staging bytes + barriers per Q-row
// halve, K/V L2 traffic halves (each b's K/V now read by 8 blocks not 16).
// Staging: 1 K-load + 1 V-load per wave (row-octet = wv). LDS 48KB ->
// 2 blocks/CU x 8 waves = 16 waves/CU (same as before).
// convert/qkv/tail_fused unchanged from r16 (verified).
typedef unsigned short u16;
typedef __attribute__((ext_vector_type(8))) short short8;   // 8 bf16 (4 VGPRs)
typedef __attribute__((ext_vector_type(4))) float f32x4;    // MFMA accumulator

__device__ __forceinline__ u16 f2bf(float f) {  // RNE
  unsigned int i = __float_as_uint(f);
  i += 0x7fffu + ((i >> 16) & 1u);
  return (u16)(i >> 16);
}

__device__ __forceinline__ short8 cvt8(const float* p) {
  float4 a = ((const float4*)p)[0];
  float4 b = ((const float4*)p)[1];
  short8 r;
  r[0] = (short)f2bf(a.x); r[1] = (short)f2bf(a.y);
  r[2] = (short)f2bf(a.z); r[3] = (short)f2bf(a.w);
  r[4] = (short)f2bf(b.x); r[5] = (short)f2bf(b.y);
  r[6] = (short)f2bf(b.z); r[7] = (short)f2bf(b.w);
  return r;
}

// ---------------------------------------------------------------------------
// Kernel 0: one-shot fp32 -> bf16 conversion of q/k/v/W_in/W_out. (unchanged)
// ---------------------------------------------------------------------------
__global__ __launch_bounds__(256) void convert_bf16(
    const float* __restrict__ q, const float* __restrict__ k,
    const float* __restrict__ v, const float* __restrict__ Wi,
    const float* __restrict__ Wo,
    u16* __restrict__ qb, u16* __restrict__ kb, u16* __restrict__ vb,
    u16* __restrict__ Wib, u16* __restrict__ Wob)
{
  const float* src; u16* dst; int len8;
  switch (blockIdx.y) {
    case 0:  src = q;  dst = qb;  len8 = 524288; break;  // 4M elts
    case 1:  src = k;  dst = kb;  len8 = 524288; break;
    case 2:  src = v;  dst = vb;  len8 = 524288; break;
    case 3:  src = Wi; dst = Wib; len8 = 393216; break;  // 3M elts
    default: src = Wo; dst = Wob; len8 = 131072; break;  // 1M elts
  }
  int stride = gridDim.x * 256;
  for (int i = blockIdx.x * 256 + threadIdx.x; i < len8; i += stride)
    *(short8*)(dst + (size_t)i * 8) = cvt8(src + (size_t)i * 8);
}

// ---------------------------------------------------------------------------
// Kernel 1: packed QKV projection. (unchanged from r13 -- verified)
// 128x128 tile, BK=32, 3-buffer counted-vmcnt pipeline, coalesced epilogue.
// ---------------------------------------------------------------------------
__global__ __launch_bounds__(256) void qkv_gemm(
    const u16* __restrict__ qb, const u16* __restrict__ kb,
    const u16* __restrict__ vb, const u16* __restrict__ W,
    const float* __restrict__ bias,
    u16* __restrict__ qh, u16* __restrict__ kh, u16* __restrict__ vt)
{
  __shared__ __align__(16) u16 SH[24576];

  const int tid  = threadIdx.x;
  const int wave = tid >> 6;
  const int lane = tid & 63;
  const int r    = lane & 15;
  const int q4   = lane >> 4;
  const int wm   = wave >> 1;
  const int wn   = wave & 1;

  const int orig = blockIdx.y * 24 + blockIdx.x;
  const int nid  = (orig & 7) * 96 + (orig >> 3);
  const int mt   = nid / 24;
  const int jt   = nid - mt * 24;
  const int src  = jt >> 3;
  const u16* X = (src == 0) ? qb : (src == 1) ? kb : vb;
  const int m0 = mt * 128;
  const int j0 = jt * 128;

  const int lrow = lane >> 2;
  const int lchk = ((lane & 3) ^ ((lane >> 3) & 3)) << 4;
  const char* Xc = (const char*)X;
  const char* Wc = (const char*)W;
  const int fchk = (q4 ^ ((r >> 1) & 3)) << 3;

  f32x4 acc[4][4];
  #pragma unroll
  for (int a = 0; a < 4; ++a)
    #pragma unroll
    for (int b = 0; b < 4; ++b)
      acc[a][b] = (f32x4){0.f, 0.f, 0.f, 0.f};

  auto STAGE = [&](int buf, int kt) {   // 4 gload_lds per wave
    const int kbyte = kt * 64;
    u16* Ad = SH + buf * 4096;
    u16* Bd = SH + 12288 + buf * 4096;
    #pragma unroll
    for (int i = 0; i < 2; ++i) {
      const int g = wave * 2 + i;
      __builtin_amdgcn_global_load_lds(
          (const u16*)(Xc + (size_t)(m0 + g * 16 + lrow) * 2048 + kbyte + lchk),
          Ad + g * 512, 16, 0, 0);
      __builtin_amdgcn_global_load_lds(
          (const u16*)(Wc + (size_t)(j0 + g * 16 + lrow) * 2048 + kbyte + lchk),
          Bd + g * 512, 16, 0, 0);
    }
  };

  auto COMPUTE = [&](int cb) {
    const u16* As = SH + cb * 4096;
    const u16* Bs = SH + 12288 + cb * 4096;
    short8 af[4], bf[4];
    #pragma unroll
    for (int mi = 0; mi < 4; ++mi)
      af[mi] = *(const short8*)(&As[(wm * 64 + mi * 16 + r) * 32 + fchk]);
    #pragma unroll
    for (int ji = 0; ji < 4; ++ji)
      bf[ji] = *(const short8*)(&Bs[(wn * 64 + ji * 16 + r) * 32 + fchk]);
    #pragma unroll
    for (int mi = 0; mi < 4; ++mi)
      #pragma unroll
      for (int ji = 0; ji < 4; ++ji)
        acc[mi][ji] = __builtin_amdgcn_mfma_f32_16x16x32_bf16(af[mi], bf[ji], acc[mi][ji], 0, 0, 0);
  };

  STAGE(0, 0);
  STAGE(1, 1);
  int cb = 0;
  for (int kt = 0; kt < 31; ++kt) {
    asm volatile("s_waitcnt vmcnt(4) lgkmcnt(0)\n\ts_barrier" ::: "memory");
    if (kt < 30) {
      int nb = cb + 2; if (nb >= 3) nb -= 3;
      STAGE(nb, kt + 2);
    }
    COMPUTE(cb);
    if (++cb == 3) cb = 0;
  }
  asm volatile("s_waitcnt vmcnt(0) lgkmcnt(0)\n\ts_barrier" ::: "memory");
  COMPUTE(cb);

  __syncthreads();
  const int h0 = (j0 & 1023) >> 6;
  const int t0 = mt * 32;
  if (src < 2) {
    #pragma unroll
    for (int mi = 0; mi < 4; ++mi) {
      const int tt = wm * 16 + mi * 4 + q4;
      #pragma unroll
      for (int ji = 0; ji < 4; ++ji) {
        const int jj = wn * 64 + ji * 16 + r;
        const int dd = jj & 63, hq = jj >> 6;
        const int cs = (((dd >> 3) ^ (tt & 7)) << 3) + (dd & 7);
        #pragma unroll
        for (int rr = 0; rr < 4; ++rr) {
          float v = acc[mi][ji][rr] + bias[j0 + jj];
          SH[((rr * 2 + hq) * 32 + tt) * 64 + cs] =
              (src == 0) ? f2bf(v * 0.125f) : f2bf(v);
        }
      }
    }
    __syncthreads();
    u16* dst = (src == 0) ? qh : kh;
    #pragma unroll
    for (int c = 0; c < 8; ++c) {
      const int cid = c * 256 + tid;
      const int nn = cid >> 9, hq = (cid >> 8) & 1, tt = (cid >> 3) & 31, dc = cid & 7;
      short8 vv = *(const short8*)(SH + ((nn * 2 + hq) * 32 + tt) * 64 +
                                   ((dc ^ (tt & 7)) << 3));
      *(short8*)(dst + (size_t)(nn * 16 + h0 + hq) * 65536 +
                 (size_t)(t0 + tt) * 64 + dc * 8) = vv;
    }
  } else {
    #pragma unroll
    for (int mi = 0; mi < 4; ++mi) {
      const int tt = wm * 16 + mi * 4 + q4;
      const int tc = tt >> 3, toff = tt & 7;
      #pragma unroll
      for (int ji = 0; ji < 4; ++ji) {
        const int jj = wn * 64 + ji * 16 + r;
        const int dd = jj & 63, hq = jj >> 6;
        #pragma unroll
        for (int rr = 0; rr < 4; ++rr) {
          float v = acc[mi][ji][rr] + bias[j0 + jj];
          SH[((rr * 2 + hq) * 64 + dd) * 32 + ((tc ^ (dd & 3)) << 3) + toff] = f2bf(v);
        }
      }
    }
    __syncthreads();
    #pragma unroll
    for (int c = 0; c < 8; ++c) {
      const int cid = c * 256 + tid;
      const int bbv = cid >> 8, dd = (cid >> 2) & 63, tc = cid & 3;
      short8 vv = *(const short8*)(SH + (bbv * 64 + dd) * 32 +
                                   ((tc ^ (dd & 3)) << 3));
      const int bb = (bbv >> 1) * 16 + h0 + (bbv & 1);
      *(short8*)(vt + (size_t)bb * 65536 + (size_t)dd * 1024 + t0 + tc * 8) = vv;
    }
  }
}

// ---------------------------------------------------------------------------
// Kernel 2: attention context. Round-17: 512 threads / 128 Q-rows per block
// (grid 8 x 64). Per-wave code identical to the verified r13 body (16 rows,
// own P buffer); 8 waves share each staged K/V tile. Staging: wave wv loads
// K row-octet wv (1 KB) and V d-octet wv (1 KB). LDS 48 KB.
// ---------------------------------------------------------------------------
__global__ __launch_bounds__(512) void attn_ctx_mfma(
    const u16* __restrict__ qh, const u16* __restrict__ kh,
    const u16* __restrict__ vt, u16* __restrict__ ctx,
    float* __restrict__ Zbuf)
{
  __shared__ __align__(16) u16 Ks[2][4096];   // 64 rows x 8 chunks x 8 bf16
  __shared__ __align__(16) u16 Vs[2][4096];
  __shared__ __align__(16) u16 Pl[8][1024];   // per-wave P[16][64], swizzled

  const int tid = threadIdx.x;
  const int wv = tid >> 6, lane = tid & 63, r = lane & 15, q4 = lane >> 4;
  const int b  = blockIdx.y;
  const int lw = blockIdx.x * 128 + wv * 16;
  const int n = b >> 4, h = b & 15;

  const u16* qbase = qh + (size_t)b * 65536;
  const char* kc = (const char*)(kh + (size_t)b * 65536);
  const char* vc = (const char*)(vt + (size_t)b * 65536);
  u16* P = Pl[wv];

  const int ls  = lane >> 3;               // row-in-octet 0..7
  const int swzb = ((lane & 7) ^ ls) << 4; // swizzled 16B-chunk byte offset
  // wave wv stages K row-octet wv and V d-octet wv (1 KB each)
  const size_t klo = (size_t)wv * 1024  + (size_t)ls * 128  + swzb;  // K row = 128 B
  const size_t vlo = (size_t)wv * 16384 + (size_t)ls * 2048 + swzb;  // V row = 2048 B

  const int rsw = r & 7;
  const int c0 = (q4 ^ rsw) << 3;          // u16 offset of logical chunk q4
  const int c1 = ((q4 ^ rsw) ^ 4) << 3;    // logical chunk q4+4

  short8 aq0 = *(const short8*)(qbase + (size_t)(lw + r) * 64 + q4 * 8);
  short8 aq1 = *(const short8*)(qbase + (size_t)(lw + r) * 64 + 32 + q4 * 8);

  f32x4 oc[4];
  #pragma unroll
  for (int ji = 0; ji < 4; ++ji) oc[ji] = (f32x4){0.f, 0.f, 0.f, 0.f};
  float z[4] = {0.f, 0.f, 0.f, 0.f};

  {
    __builtin_amdgcn_global_load_lds(kc + klo, &Ks[0][wv * 512], 16, 0, 0);
    __builtin_amdgcn_global_load_lds(vc + vlo, &Vs[0][wv * 512], 16, 0, 0);
  }

  for (int it = 0; it < 16; ++it) {
    const int cur = it & 1;
    __syncthreads();   // drains vmcnt -> Ks/Vs[cur] staged; prev-iter reads done
    const u16* Kb = Ks[cur];
    const u16* Vb = Vs[cur];

    f32x4 sc[4];
    #pragma unroll
    for (int ji = 0; ji < 4; ++ji) {
      const int row = (ji * 16 + r) * 64;
      short8 bk0 = *(const short8*)(Kb + row + c0);
      short8 bk1 = *(const short8*)(Kb + row + c1);
      f32x4 t = (f32x4){0.f, 0.f, 0.f, 0.f};
      t = __builtin_amdgcn_mfma_f32_16x16x32_bf16(aq0, bk0, t, 0, 0, 0);
      t = __builtin_amdgcn_mfma_f32_16x16x32_bf16(aq1, bk1, t, 0, 0, 0);
      sc[ji] = t;
    }

    if (it < 15) {
      __builtin_amdgcn_global_load_lds(kc + (size_t)(it + 1) * 8192 + klo,
                                       &Ks[cur ^ 1][wv * 512], 16, 0, 0);
      __builtin_amdgcn_global_load_lds(vc + (size_t)(it + 1) * 128 + vlo,
                                       &Vs[cur ^ 1][wv * 512], 16, 0, 0);
    }

    #pragma unroll
    for (int ji = 0; ji < 4; ++ji) {
      const int cw = ji * 2 + (r >> 3);   // logical 8-elt chunk of col ji*16+r
      #pragma unroll
      for (int rr = 0; rr < 4; ++rr) {
        float e = __expf(sc[ji][rr]);
        z[rr] += e;
        const int row = q4 * 4 + rr;
        P[row * 64 + ((cw ^ (row & 7)) << 3) + (r & 7)] = f2bf(e);
      }
    }
    asm volatile("s_waitcnt lgkmcnt(0)" ::: "memory");
    short8 ap0 = *(const short8*)(P + r * 64 + c0);
    short8 ap1 = *(const short8*)(P + r * 64 + c1);
    #pragma unroll
    for (int ji = 0; ji < 4; ++ji) {
      const int row = (ji * 16 + r) * 64;
      short8 bv0 = *(const short8*)(Vb + row + c0);
      short8 bv1 = *(const short8*)(Vb + row + c1);
      oc[ji] = __builtin_amdgcn_mfma_f32_16x16x32_bf16(ap0, bv0, oc[ji], 0, 0, 0);
      oc[ji] = __builtin_amdgcn_mfma_f32_16x16x32_bf16(ap1, bv1, oc[ji], 0, 0, 0);
    }
  }

  #pragma unroll
  for (int rr = 0; rr < 4; ++rr) {
    float zz = z[rr];
    zz += __shfl_xor(zz, 1);
    zz += __shfl_xor(zz, 2);
    zz += __shfl_xor(zz, 4);
    zz += __shfl_xor(zz, 8);
    z[rr] = zz;
  }

  #pragma unroll
  for (int rr = 0; rr < 4; ++rr) {
    float inv = 1.0f / z[rr];
    int l = lw + q4 * 4 + rr;
    u16* crow = ctx + ((size_t)l * 4 + n) * 1024 + h * 64;
    #pragma unroll
    for (int ji = 0; ji < 4; ++ji)
      crow[ji * 16 + r] = f2bf(oc[ji][rr] * inv);
    if (r == 0) Zbuf[(size_t)b * 1024 + l] = z[rr];
  }
}

// ---------------------------------------------------------------------------
// Kernel 3: fused tail -- out_gemm (blocks 0..511) + attn_w (blocks 512..1535).
// (unchanged from r16 -- verified)
// ---------------------------------------------------------------------------
__global__ __launch_bounds__(256) void tail_fused(
    const u16* __restrict__ qh, const u16* __restrict__ kh,
    const float* __restrict__ Zbuf, float* __restrict__ out_w,
    const u16* __restrict__ ctx, const u16* __restrict__ W,
    const float* __restrict__ bias, float* __restrict__ out)
{
  __shared__ __align__(16) u16 SH[18432];   // 36 KB

  const int tid = threadIdx.x;
  const int wv = tid >> 6, lane = tid & 63, r = lane & 15, q4 = lane >> 4;

  if (blockIdx.x < 512) {
    // ---------------- out_gemm body (r13, verified) ----------------
    const int wave = wv;
    const int wm   = wave >> 1;
    const int wn   = wave & 1;
    const int orig = blockIdx.x;
    const int nid  = (orig & 7) * 64 + (orig >> 3);
    const int mt   = nid >> 4;
    const int jt   = nid & 15;
    const int m0 = mt * 128;
    const int j0 = jt * 64;

    const int lrow = lane >> 2;
    const int lchk = ((lane & 3) ^ ((lane >> 3) & 3)) << 4;
    const char* Ac = (const char*)ctx;
    const char* Wc = (const char*)W;
    const int fchk = (q4 ^ ((r >> 1) & 3)) << 3;

    f32x4 acc[4][2];
    #pragma unroll
    for (int a = 0; a < 4; ++a)
      #pragma unroll
      for (int b = 0; b < 2; ++b)
        acc[a][b] = (f32x4){0.f, 0.f, 0.f, 0.f};

    auto STAGE = [&](int buf, int kt) {   // 3 gload_lds per wave
      const int kbyte = kt * 64;
      u16* Ad = SH + buf * 4096;
      u16* Bd = SH + 12288 + buf * 2048;
      #pragma unroll
      for (int i = 0; i < 2; ++i) {
        const int g = wave * 2 + i;
        __builtin_amdgcn_global_load_lds(
            (const u16*)(Ac + (size_t)(m0 + g * 16 + lrow) * 2048 + kbyte + lchk),
            Ad + g * 512, 16, 0, 0);
      }
      __builtin_amdgcn_global_load_lds(
          (const u16*)(Wc + (size_t)(j0 + wave * 16 + lrow) * 2048 + kbyte + lchk),
          Bd + wave * 512, 16, 0, 0);
    };

    auto COMPUTE = [&](int cb) {
      const u16* As = SH + cb * 4096;
      const u16* Bs = SH + 12288 + cb * 2048;
      short8 af[4], bf[2];
      #pragma unroll
      for (int mi = 0; mi < 4; ++mi)
        af[mi] = *(const short8*)(&As[(wm * 64 + mi * 16 + r) * 32 + fchk]);
      #pragma unroll
      for (int ji = 0; ji < 2; ++ji)
        bf[ji] = *(const short8*)(&Bs[(wn * 32 + ji * 16 + r) * 32 + fchk]);
      #pragma unroll
      for (int mi = 0; mi < 4; ++mi)
        #pragma unroll
        for (int ji = 0; ji < 2; ++ji)
          acc[mi][ji] = __builtin_amdgcn_mfma_f32_16x16x32_bf16(af[mi], bf[ji], acc[mi][ji], 0, 0, 0);
    };

    STAGE(0, 0);
    STAGE(1, 1);
    int cb = 0;
    for (int kt = 0; kt < 31; ++kt) {
      asm volatile("s_waitcnt vmcnt(3) lgkmcnt(0)\n\ts_barrier" ::: "memory");
      if (kt < 30) {
        int nb = cb + 2; if (nb >= 3) nb -= 3;
        STAGE(nb, kt + 2);
      }
      COMPUTE(cb);
      if (++cb == 3) cb = 0;
    }
    asm volatile("s_waitcnt vmcnt(0) lgkmcnt(0)\n\ts_barrier" ::: "memory");
    COMPUTE(cb);

    #pragma unroll
    for (int mi = 0; mi < 4; ++mi) {
      #pragma unroll
      for (int ji = 0; ji < 2; ++ji) {
        #pragma unroll
        for (int rr = 0; rr < 4; ++rr) {
          int m = m0 + wm * 64 + mi * 16 + q4 * 4 + rr;
          int j = j0 + wn * 32 + ji * 16 + r;
          out[(size_t)m * 1024 + j] = acc[mi][ji][rr] + bias[j];
        }
      }
    }
  } else {
    // ---------------- attn_w body: 3-buffer counted-vmcnt head loop --------
    const int id2 = blockIdx.x - 512;
    const int lt = id2 & 15;
    const int st = (id2 >> 4) & 15;
    const int n  = id2 >> 8;
    const int l0 = lt * 64;
    const int s0 = st * 64;
    const int lw = l0 + wv * 16;

    u16* Kw = SH;                              // 3 x 4096 u16 = 24 KB
    float* invZ = (float*)(SH + 12288);        // 16*64 floats = 4 KB

    const char* khc = (const char*)kh + (size_t)n * 2097152;

    const int ls  = lane >> 3;
    const int swzb = ((lane & 7) ^ ls) << 4;
    const int iw  = wv * 2;
    const size_t klo = (size_t)s0 * 128 + (size_t)iw * 1024 + (size_t)ls * 128 + swzb;

    const int rsw = r & 7;
    const int c0 = (q4 ^ rsw) << 3;
    const int c1 = ((q4 ^ rsw) ^ 4) << 3;

    for (int i = tid; i < 1024; i += 256) {
      int hh = i >> 6, row = i & 63;
      invZ[hh * 64 + row] = 1.0f / (Zbuf[(size_t)(n * 16 + hh) * 1024 + l0 + row] * 16.0f);
    }

    auto STAGEK = [&](int buf, int hh) {   // 2 gload_lds per wave
      const char* kp = khc + (size_t)hh * 131072 + klo;
      u16* kd = &Kw[buf * 4096 + iw * 512];
      __builtin_amdgcn_global_load_lds(kp,        kd,       16, 0, 0);
      __builtin_amdgcn_global_load_lds(kp + 1024, kd + 512, 16, 0, 0);
    };

    STAGEK(0, 0);
    STAGEK(1, 1);
    const u16* q0 = qh + (size_t)(n * 16) * 65536;
    short8 aqc0 = *(const short8*)(q0 + (size_t)(lw + r) * 64 + q4 * 8);
    short8 aqc1 = *(const short8*)(q0 + (size_t)(lw + r) * 64 + 32 + q4 * 8);

    f32x4 wacc[4];
    #pragma unroll
    for (int ji = 0; ji < 4; ++ji) wacc[ji] = (f32x4){0.f, 0.f, 0.f, 0.f};

    auto HEAD = [&](int hh, int cbw, short8& an0, short8& an1) {
      const int hn = (hh < 15) ? hh + 1 : hh;
      const u16* qn = qh + (size_t)(n * 16 + hn) * 65536;
      an0 = *(const short8*)(qn + (size_t)(lw + r) * 64 + q4 * 8);
      an1 = *(const short8*)(qn + (size_t)(lw + r) * 64 + 32 + q4 * 8);
      if (hh < 14) {
        int nb = cbw + 2; if (nb >= 3) nb -= 3;
        STAGEK(nb, hh + 2);
      }
      const u16* Kb = Kw + cbw * 4096;
      f32x4 sc[4];
      #pragma unroll
      for (int ji = 0; ji < 4; ++ji) {
        const int row = (ji * 16 + r) * 64;
        short8 bk0 = *(const short8*)(Kb + row + c0);
        short8 bk1 = *(const short8*)(Kb + row + c1);
        f32x4 t = (f32x4){0.f, 0.f, 0.f, 0.f};
        t = __builtin_amdgcn_mfma_f32_16x16x32_bf16(aqc0, bk0, t, 0, 0, 0);
        t = __builtin_amdgcn_mfma_f32_16x16x32_bf16(aqc1, bk1, t, 0, 0, 0);
        sc[ji] = t;
      }
      #pragma unroll
      for (int rr = 0; rr < 4; ++rr) {
        float iv = invZ[hh * 64 + wv * 16 + q4 * 4 + rr];
        #pragma unroll
        for (int ji = 0; ji < 4; ++ji)
          wacc[ji][rr] += __expf(sc[ji][rr]) * iv;
      }
      aqc0 = an0; aqc1 = an1;
    };

    int cbw = 0;
    short8 an0, an1;
    for (int hh = 0; hh < 15; ++hh) {
      asm volatile("s_waitcnt vmcnt(4) lgkmcnt(0)\n\ts_barrier" ::: "memory");
      HEAD(hh, cbw, an0, an1);
      if (++cbw == 3) cbw = 0;
    }
    asm volatile("s_waitcnt vmcnt(0) lgkmcnt(0)\n\ts_barrier" ::: "memory");
    HEAD(15, cbw, an0, an1);

    #pragma unroll
    for (int ji = 0; ji < 4; ++ji)
      #pragma unroll
      for (int rr = 0; rr < 4; ++rr) {
        int row = lw + q4 * 4 + rr;
        int col = s0 + ji * 16 + r;
        out_w[(size_t)n * 1048576 + (size_t)row * 1024 + col] = wacc[ji][rr];
      }
  }
}

// ---------------------------------------------------------------------------
extern "C" void kernel_launch(void* const* d_in, const int* in_sizes, int n_in,
                              void* d_out, int out_size, void* d_ws, size_t ws_size,
                              hipStream_t stream) {
  const float* query = (const float*)d_in[0];
  const float* key   = (const float*)d_in[1];
  const float* value = (const float*)d_in[2];
  const float* W_in  = (const float*)d_in[3];
  const float* b_in  = (const float*)d_in[4];
  const float* W_out = (const float*)d_in[5];
  const float* b_out = (const float*)d_in[6];
  float* out = (float*)d_out;

  // ws (~64.3 MB): qb 8 | kb 8 | vb 8 | Wib 6 | Wob 2 | qh 8 | kh 8 | vt 8 | ctx 8 | Z .25
  u16* qb  = (u16*)d_ws;
  u16* kb  = qb  + (size_t)4194304;
  u16* vb  = kb  + (size_t)4194304;
  u16* Wib = vb  + (size_t)4194304;
  u16* Wob = Wib + (size_t)3145728;
  u16* qh  = Wob + (size_t)1048576;
  u16* kh  = qh  + (size_t)4194304;
  u16* vt  = kh  + (size_t)4194304;
  u16* ctx = vt  + (size_t)4194304;
  float* Zbuf = (float*)(ctx + (size_t)4194304);

  convert_bf16<<<dim3(512, 5), 256, 0, stream>>>(query, key, value, W_in, W_out,
                                                 qb, kb, vb, Wib, Wob);
  qkv_gemm<<<dim3(24, 32), 256, 0, stream>>>(qb, kb, vb, Wib, b_in, qh, kh, vt);
  attn_ctx_mfma<<<dim3(8, 64), 512, 0, stream>>>(qh, kh, vt, ctx, Zbuf);
  tail_fused<<<dim3(1536), 256, 0, stream>>>(qh, kh, Zbuf, out + (size_t)4194304,
                                             ctx, Wob, b_out, out);
}